// Round 4
// baseline (3920.278 us; speedup 1.0000x reference)
//
#include <hip/hip_runtime.h>
#include <hip/hip_bf16.h>
#include <stdint.h>

#define GN   6000
#define GFIN 512
#define GNH  8
#define GNC  40
#define WPR  192          // bitmask words per row (192*32 = 6144 >= 6000)
#define NW   188          // words actually swept (188*32 = 6016 >= 6000)

__device__ __forceinline__ float bf2f(uint16_t b){
  union { uint32_t u; float f; } v; v.u = ((uint32_t)b) << 16; return v.f;
}
__device__ __forceinline__ uint16_t f2bf(float f){
  uint32_t u = __float_as_uint(f);
  return (uint16_t)((u + 0x7FFFu + ((u >> 16) & 1u)) >> 16);
}

// ---- prep: pad W2/a2 to 64 cols; zero read-pads (Wh1 pad rows, p1/q1 tails) ----
__global__ void k_prep(const float* __restrict__ W2, const float* __restrict__ as2,
                       const float* __restrict__ at2,
                       float* __restrict__ W2f, float* __restrict__ as2f,
                       float* __restrict__ at2f,
                       uint32_t* __restrict__ Wh1u, float* __restrict__ p1,
                       float* __restrict__ q1){
  int i = blockIdx.x * 256 + threadIdx.x;
  if (i < GFIN*64) { int f = i >> 6, c = i & 63; W2f[i] = (c < GNC) ? W2[f*GNC + c] : 0.f; }
  if (i < 64) { as2f[i] = (i < GNC) ? as2[i] : 0.f; at2f[i] = (i < GNC) ? at2[i] : 0.f; }
  if (i < 80*32) Wh1u[(size_t)GNH*GN*32 + i] = 0u;          // 80 pad rows (bf16 pairs)
  if (i < 128) { p1[GNH*GN + i] = 0.f; q1[GNH*GN + i] = 0.f; }
}

// ---- adjacency -> bitmask + f32 echo to d_out (single pass over adj) ----
__global__ void k_bitmask(const int* __restrict__ adj, uint32_t* __restrict__ bm,
                          float* __restrict__ echo){
  int idx = blockIdx.x * 256 + threadIdx.x;
  if (idx >= GN * WPR) return;
  int row = idx / WPR, w = idx - row * WPR;
  int j0 = w * 32;
  uint32_t bits = 0u;
  if (j0 < GN) {
    const int* a = adj + (size_t)row * GN + j0;
    float* e = echo + (size_t)row * GN + j0;
    int lim = GN - j0;
    if (lim >= 32) {
      const int4* a4 = (const int4*)a;
      float4* e4 = (float4*)e;
      #pragma unroll
      for (int g = 0; g < 8; ++g) {
        int4 v = a4[g];
        float4 f;
        f.x = (v.x != 0) ? 1.f : 0.f;
        f.y = (v.y != 0) ? 1.f : 0.f;
        f.z = (v.z != 0) ? 1.f : 0.f;
        f.w = (v.w != 0) ? 1.f : 0.f;
        e4[g] = f;
        bits |= (v.x != 0 ? 1u : 0u) << (4*g);
        bits |= (v.y != 0 ? 1u : 0u) << (4*g + 1);
        bits |= (v.z != 0 ? 1u : 0u) << (4*g + 2);
        bits |= (v.w != 0 ? 1u : 0u) << (4*g + 3);
      }
    } else {
      for (int b = 0; b < lim; ++b) {
        int v = a[b];
        e[b] = (v != 0) ? 1.f : 0.f;
        bits |= (v != 0 ? 1u : 0u) << b;
      }
    }
  }
  bm[idx] = bits;
}

// ---- layer-1 GEMM: x[6000,512] @ W1[h,512,64] -> Wh1 bf16, scores f32 ----
__global__ __launch_bounds__(256) void k_gemm1(
    const float* __restrict__ x, const float* __restrict__ W1,
    const float* __restrict__ as1, const float* __restrict__ at1,
    uint16_t* __restrict__ Wh1bf, float* __restrict__ ss1, float* __restrict__ st1){
  int lane = threadIdx.x & 63;
  int wid  = threadIdx.x >> 6;
  int h = blockIdx.y;
  int row = blockIdx.x * 4 + wid;
  const float* W = W1 + (size_t)h * GFIN * 64 + lane;
  const float* xr = x + (size_t)row * GFIN;
  float acc0 = 0.f, acc1 = 0.f;
  #pragma unroll 8
  for (int f = 0; f < GFIN; f += 2) {
    acc0 = fmaf(xr[f],   W[f*64],     acc0);
    acc1 = fmaf(xr[f+1], W[(f+1)*64], acc1);
  }
  float acc = acc0 + acc1;
  Wh1bf[((size_t)h * GN + row) * 64 + lane] = f2bf(acc);
  float rs = as1[h*64 + lane] * acc;
  float rt = at1[h*64 + lane] * acc;
  #pragma unroll
  for (int d = 32; d; d >>= 1) { rs += __shfl_xor(rs, d, 64); rt += __shfl_xor(rt, d, 64); }
  if (lane == 0) { ss1[(size_t)h*GN + row] = rs; st1[(size_t)h*GN + row] = rt; }
}

// ---- column stats: p=exp(s), q=exp(0.2 s), m=max(s) (per head-block) ----
__global__ void k_stats(const float* __restrict__ s_tgt, float* __restrict__ p,
                        float* __restrict__ q, float* __restrict__ m){
  int h = blockIdx.x;
  __shared__ float red[256];
  float mx = -3.0e38f;
  for (int n = threadIdx.x; n < GN; n += 256) {
    float s = s_tgt[(size_t)h*GN + n];
    p[(size_t)h*GN + n] = expf(s);
    q[(size_t)h*GN + n] = expf(0.2f * s);
    mx = fmaxf(mx, s);
  }
  red[threadIdx.x] = mx;
  __syncthreads();
  for (int d = 128; d > 0; d >>= 1) {
    if (threadIdx.x < d) red[threadIdx.x] = fmaxf(red[threadIdx.x], red[threadIdx.x + d]);
    __syncthreads();
  }
  if (threadIdx.x == 0) m[h] = red[0];
}

// ---- layer-1 attention: thread-per-row, 32 outputs per thread (o-half split),
//      normalize + ELU + bf16 h1 write fused.
//      exp(LR(si+sj)-M) = (si+sj>0) ? ci*pj : di*qj  (exact; M cancels in acc/Z)
__global__ __launch_bounds__(256) void k_attn1(
    const uint32_t* __restrict__ bm, const uint32_t* __restrict__ Wh1u,
    const float* __restrict__ ss1, const float* __restrict__ p1,
    const float* __restrict__ q1, const float* __restrict__ m1,
    uint16_t* __restrict__ h1bf){
  int i  = blockIdx.x * 256 + threadIdx.x;   // row
  int oh = blockIdx.y;                       // output half: o in [oh*32, oh*32+32)
  int h  = blockIdx.z;
  bool active = (i < GN);
  int ii = active ? i : 0;
  float si = ss1[(size_t)h*GN + ii];
  float mh = m1[h];
  float sm = si + mh;
  float M  = sm > 0.f ? sm : 0.2f * sm;
  float ci = expf(si - M);
  float di = expf(0.2f * si - M);
  float ethr = expf(-si);                    // pj > ethr  <=>  si + sj > 0
  float accL[16], accH[16];
  #pragma unroll
  for (int k = 0; k < 16; ++k) { accL[k] = 0.f; accH[k] = 0.f; }
  float Z = 0.f;
  const float* ph = p1 + (size_t)h * GN;
  const float* qh = q1 + (size_t)h * GN;
  const uint32_t* whu = Wh1u + (size_t)h * GN * 32 + oh * 16;  // bf16-pair rows
  const uint32_t* bmr = bm + (size_t)ii * WPR;
  for (int w = 0; w < NW; ++w) {
    uint32_t bits = bmr[w];
    int jb = w * 32;
    #pragma unroll 4
    for (int b = 0; b < 32; ++b) {
      float pj = ph[jb + b];
      float qj = qh[jb + b];
      float wsel = (pj > ethr) ? (ci * pj) : (di * qj);
      float wv = ((bits >> b) & 1u) ? wsel : 0.f;
      Z += wv;
      const uint32_t* wr = whu + (size_t)(jb + b) * 32;
      #pragma unroll
      for (int k = 0; k < 16; ++k) {
        uint32_t u = wr[k];
        accL[k] = fmaf(wv, __uint_as_float(u << 16),          accL[k]);
        accH[k] = fmaf(wv, __uint_as_float(u & 0xFFFF0000u),  accH[k]);
      }
    }
  }
  if (!active) return;
  float inv = 1.f / Z;
  uint16_t* hrow = h1bf + (size_t)i * GFIN + h * 64 + oh * 32;
  #pragma unroll
  for (int k = 0; k < 16; ++k) {
    float vL = accL[k] * inv;
    float vH = accH[k] * inv;
    vL = vL > 0.f ? vL : (expf(vL) - 1.f);   // ELU
    vH = vH > 0.f ? vH : (expf(vH) - 1.f);
    hrow[2*k]   = f2bf(vL);
    hrow[2*k+1] = f2bf(vH);
  }
}

// ---- layer-2 GEMM: h1(bf16)[6000,512] @ W2f[512,64] -> Wh2 bf16, scores f32 ----
__global__ __launch_bounds__(256) void k_gemm2(
    const uint16_t* __restrict__ h1bf, const float* __restrict__ W2f,
    const float* __restrict__ as2f, const float* __restrict__ at2f,
    uint16_t* __restrict__ Wh2bf, float* __restrict__ ss2, float* __restrict__ st2){
  int lane = threadIdx.x & 63;
  int wid  = threadIdx.x >> 6;
  int row = blockIdx.x * 4 + wid;
  const uint32_t* xr = (const uint32_t*)(h1bf + (size_t)row * GFIN);
  const float* W = W2f + lane;
  float acc = 0.f;
  #pragma unroll 8
  for (int fp = 0; fp < GFIN/2; ++fp) {
    uint32_t u = xr[fp];
    acc = fmaf(__uint_as_float(u << 16),         W[(2*fp)*64],   acc);
    acc = fmaf(__uint_as_float(u & 0xFFFF0000u), W[(2*fp+1)*64], acc);
  }
  Wh2bf[(size_t)row * 64 + lane] = f2bf(acc);
  float rs = as2f[lane] * acc;
  float rt = at2f[lane] * acc;
  #pragma unroll
  for (int d = 32; d; d >>= 1) { rs += __shfl_xor(rs, d, 64); rt += __shfl_xor(rt, d, 64); }
  if (lane == 0) { ss2[row] = rs; st2[row] = rt; }
}

// ---- layer-2 attention: wave-per-row, uniform ctz loop over set bits,
//      direct f32 logit write ----
__global__ __launch_bounds__(256) void k_attn2(
    const uint32_t* __restrict__ bm, const uint16_t* __restrict__ Wh2bf,
    const float* __restrict__ ss2, const float* __restrict__ p2,
    const float* __restrict__ q2, const float* __restrict__ m2,
    float* __restrict__ out){
  int lane = threadIdx.x & 63;
  int wid  = threadIdx.x >> 6;
  int row = blockIdx.x * 4 + wid;
  float si = ss2[row];
  float mh = m2[0];
  float sm = si + mh;
  float M  = sm > 0.f ? sm : 0.2f * sm;
  float ci = expf(si - M);
  float di = expf(0.2f * si - M);
  float ethr = expf(-si);
  float acc = 0.f, Z = 0.f;
  const uint32_t* bmr = bm + (size_t)row * WPR;
  for (int w = 0; w < NW; ++w) {
    uint32_t bits = bmr[w];          // wave-uniform
    int jb = w * 32;
    while (bits) {
      int b = __builtin_ctz(bits);
      bits &= bits - 1u;
      int j = jb + b;
      float pj = p2[j];
      float qj = q2[j];
      float wsel = (pj > ethr) ? (ci * pj) : (di * qj);
      Z += wsel;
      acc = fmaf(wsel, bf2f(Wh2bf[(size_t)j * 64 + lane]), acc);
    }
  }
  if (lane < GNC) out[(size_t)row * GNC + lane] = acc / Z;
}

extern "C" void kernel_launch(void* const* d_in, const int* in_sizes, int n_in,
                              void* d_out, int out_size, void* d_ws, size_t ws_size,
                              hipStream_t stream){
  const float* x   = (const float*)d_in[0];
  const int*   adj = (const int*)d_in[1];
  const float* W1  = (const float*)d_in[2];
  const float* as1 = (const float*)d_in[3];
  const float* at1 = (const float*)d_in[4];
  const float* W2  = (const float*)d_in[5];
  const float* as2 = (const float*)d_in[6];
  const float* at2 = (const float*)d_in[7];
  float* out    = (float*)d_out;                    // f32 logits [6000,40]
  float* outadj = out + (size_t)GN * GNC;           // f32 adjacency echo [6000,6000]
  (void)in_sizes; (void)n_in; (void)out_size; (void)ws_size;

  char* wsb = (char*)d_ws;
  size_t off = 0;
  auto alloc = [&](size_t bytes) -> void* {
    void* r = wsb + off;
    off = (off + bytes + 255) & ~(size_t)255;
    return r;
  };
  uint32_t* bm    = (uint32_t*)alloc((size_t)GN * WPR * 4);
  float*    W2f   = (float*)alloc((size_t)GFIN * 64 * 4);
  float*    as2f  = (float*)alloc(64 * 4);
  float*    at2f  = (float*)alloc(64 * 4);
  uint16_t* Wh1bf = (uint16_t*)alloc(((size_t)GNH * GN + 80) * 64 * 2);
  float*    ss1   = (float*)alloc((size_t)GNH * GN * 4);
  float*    st1   = (float*)alloc((size_t)GNH * GN * 4);
  float*    p1    = (float*)alloc(((size_t)GNH * GN + 128) * 4);
  float*    q1    = (float*)alloc(((size_t)GNH * GN + 128) * 4);
  float*    m1    = (float*)alloc(64);
  uint16_t* h1bf  = (uint16_t*)alloc((size_t)GN * GFIN * 2);
  uint16_t* Wh2bf = (uint16_t*)alloc((size_t)GN * 64 * 2);
  float*    ss2   = (float*)alloc((size_t)GN * 4);
  float*    st2   = (float*)alloc((size_t)GN * 4);
  float*    p2    = (float*)alloc(((size_t)GN + 128) * 4);
  float*    q2    = (float*)alloc(((size_t)GN + 128) * 4);
  float*    m2    = (float*)alloc(64);
  // total ~18.8 MB

  hipLaunchKernelGGL(k_prep, dim3(128), dim3(256), 0, stream,
      W2, as2, at2, W2f, as2f, at2f, (uint32_t*)Wh1bf, p1, q1);
  hipLaunchKernelGGL(k_bitmask, dim3(GN*WPR/256), dim3(256), 0, stream, adj, bm, outadj);
  hipLaunchKernelGGL(k_gemm1, dim3(GN/4, GNH), dim3(256), 0, stream,
      x, W1, as1, at1, Wh1bf, ss1, st1);
  hipLaunchKernelGGL(k_stats, dim3(GNH), dim3(256), 0, stream, st1, p1, q1, m1);
  hipLaunchKernelGGL(k_attn1, dim3((GN+255)/256, 2, GNH), dim3(256), 0, stream,
      bm, (const uint32_t*)Wh1bf, ss1, p1, q1, m1, h1bf);
  hipLaunchKernelGGL(k_gemm2, dim3(GN/4), dim3(256), 0, stream,
      h1bf, W2f, as2f, at2f, Wh2bf, ss2, st2);
  hipLaunchKernelGGL(k_stats, dim3(1), dim3(256), 0, stream, st2, p2, q2, m2);
  hipLaunchKernelGGL(k_attn2, dim3(GN/4), dim3(256), 0, stream,
      bm, Wh2bf, ss2, p2, q2, m2, out);
}

// Round 5
// 1407.506 us; speedup vs baseline: 2.7853x; 2.7853x over previous
//
#include <hip/hip_runtime.h>
#include <hip/hip_bf16.h>
#include <stdint.h>

#define GN   6000
#define GFIN 512
#define GNH  8
#define GNC  40
#define WPR  192          // bitmask words per row (192*32 = 6144 >= 6000)
#define NW   188          // words actually swept (188*32 = 6016 >= 6000)
#define NCH1 8
#define CWW1 24           // words per L1 chunk (24*32 = 768 cols)
#define NCH2 32
#define CWW2 6            // words per L2 chunk (6*32 = 192 cols)

__device__ __forceinline__ float bf2f(uint16_t b){
  union { uint32_t u; float f; } v; v.u = ((uint32_t)b) << 16; return v.f;
}
__device__ __forceinline__ uint16_t f2bf(float f){
  uint32_t u = __float_as_uint(f);
  return (uint16_t)((u + 0x7FFFu + ((u >> 16) & 1u)) >> 16);
}

// ---- prep: pad W2/a2 to 64 cols; zero all read-pads ----
__global__ void k_prep(const float* __restrict__ W2, const float* __restrict__ as2,
                       const float* __restrict__ at2,
                       float* __restrict__ W2f, float* __restrict__ as2f,
                       float* __restrict__ at2f,
                       uint32_t* __restrict__ Wh1u, uint32_t* __restrict__ Wh2u,
                       float* __restrict__ p1, float* __restrict__ q1,
                       float* __restrict__ p2, float* __restrict__ q2){
  int i = blockIdx.x * 256 + threadIdx.x;
  if (i < GFIN*64) { int f = i >> 6, c = i & 63; W2f[i] = (c < GNC) ? W2[f*GNC + c] : 0.f; }
  if (i < 64) { as2f[i] = (i < GNC) ? as2[i] : 0.f; at2f[i] = (i < GNC) ? at2[i] : 0.f; }
  if (i < 80*32) Wh1u[(size_t)GNH*GN*32 + i] = 0u;   // pad rows after head 7
  if (i < 16*32) Wh2u[(size_t)GN*32 + i] = 0u;       // Wh2 pad rows 6000..6015
  if (i < 128) { p1[GNH*GN + i] = 0.f; q1[GNH*GN + i] = 0.f;
                 p2[GN + i] = 0.f;     q2[GN + i] = 0.f; }
}

// ---- adjacency -> bitmask only (echo written last by k_echo) ----
__global__ void k_bitmask(const int* __restrict__ adj, uint32_t* __restrict__ bm){
  int idx = blockIdx.x * 256 + threadIdx.x;
  if (idx >= GN * WPR) return;
  int row = idx / WPR, w = idx - row * WPR;
  int j0 = w * 32;
  uint32_t bits = 0u;
  if (j0 < GN) {
    const int* a = adj + (size_t)row * GN + j0;
    int lim = GN - j0;
    if (lim >= 32) {
      const int4* a4 = (const int4*)a;
      #pragma unroll
      for (int g = 0; g < 8; ++g) {
        int4 v = a4[g];
        bits |= (v.x != 0 ? 1u : 0u) << (4*g);
        bits |= (v.y != 0 ? 1u : 0u) << (4*g + 1);
        bits |= (v.z != 0 ? 1u : 0u) << (4*g + 2);
        bits |= (v.w != 0 ? 1u : 0u) << (4*g + 3);
      }
    } else {
      for (int b = 0; b < lim; ++b) bits |= (a[b] != 0 ? 1u : 0u) << b;
    }
  }
  bm[idx] = bits;
}

// ---- layer-1 GEMM: 8 rows per wave (W1 column stream reused x8) ----
__global__ __launch_bounds__(256) void k_gemm1(
    const float* __restrict__ x, const float* __restrict__ W1,
    const float* __restrict__ as1, const float* __restrict__ at1,
    uint16_t* __restrict__ Wh1bf, float* __restrict__ ss1, float* __restrict__ st1){
  int lane = threadIdx.x & 63;
  int wid  = threadIdx.x >> 6;
  int h = blockIdx.y;
  int row0 = blockIdx.x * 32 + wid * 8;
  const float* W = W1 + (size_t)h * GFIN * 64 + lane;
  const float* xr[8];
  #pragma unroll
  for (int r = 0; r < 8; ++r) {
    int rc = row0 + r; if (rc > GN-1) rc = GN-1;
    xr[r] = x + (size_t)rc * GFIN;
  }
  float acc[8];
  #pragma unroll
  for (int r = 0; r < 8; ++r) acc[r] = 0.f;
  #pragma unroll 4
  for (int f = 0; f < GFIN; ++f) {
    float Wv = W[f*64];
    #pragma unroll
    for (int r = 0; r < 8; ++r) acc[r] = fmaf(xr[r][f], Wv, acc[r]);
  }
  float av = as1[h*64 + lane], tv = at1[h*64 + lane];
  #pragma unroll
  for (int r = 0; r < 8; ++r) {
    int row = row0 + r;
    if (row >= GN) break;
    Wh1bf[((size_t)h * GN + row) * 64 + lane] = f2bf(acc[r]);
    float rs = av * acc[r];
    float rt = tv * acc[r];
    #pragma unroll
    for (int d = 32; d; d >>= 1) { rs += __shfl_xor(rs, d, 64); rt += __shfl_xor(rt, d, 64); }
    if (lane == 0) { ss1[(size_t)h*GN + row] = rs; st1[(size_t)h*GN + row] = rt; }
  }
}

// ---- column stats: p=exp(s), q=exp(0.2 s), m=max(s) ----
__global__ void k_stats(const float* __restrict__ s_tgt, float* __restrict__ p,
                        float* __restrict__ q, float* __restrict__ m){
  int h = blockIdx.x;
  __shared__ float red[256];
  float mx = -3.0e38f;
  for (int n = threadIdx.x; n < GN; n += 256) {
    float s = s_tgt[(size_t)h*GN + n];
    p[(size_t)h*GN + n] = expf(s);
    q[(size_t)h*GN + n] = expf(0.2f * s);
    mx = fmaxf(mx, s);
  }
  red[threadIdx.x] = mx;
  __syncthreads();
  for (int d = 128; d > 0; d >>= 1) {
    if (threadIdx.x < d) red[threadIdx.x] = fmaxf(red[threadIdx.x], red[threadIdx.x + d]);
    __syncthreads();
  }
  if (threadIdx.x == 0) m[h] = red[0];
}

// ---- layer-1 attention, j-chunked: thread-per-row, 32 outputs, partial accumulate ----
//      exp(LR(si+sj)-M) = (si+sj>0) ? ci*pj : di*qj  (exact; M cancels in sum/Z)
__global__ __launch_bounds__(256) void k_attn1(
    const uint32_t* __restrict__ bm, const uint32_t* __restrict__ Wh1u,
    const float* __restrict__ ss1, const float* __restrict__ p1,
    const float* __restrict__ q1, const float* __restrict__ m1,
    float* __restrict__ part1, float* __restrict__ Zp1){
  int i  = blockIdx.x * 256 + threadIdx.x;   // row
  int oh = blockIdx.y;                       // output half
  int bz = blockIdx.z;
  int h  = bz >> 3;
  int ch = bz & 7;
  bool active = (i < GN);
  int ii = active ? i : 0;
  float si = ss1[(size_t)h*GN + ii];
  float mh = m1[h];
  float sm = si + mh;
  float M  = sm > 0.f ? sm : 0.2f * sm;
  float ci = expf(si - M);
  float di = expf(0.2f * si - M);
  float ethr = expf(-si);                    // pj > ethr  <=>  si + sj > 0
  float accL[16], accH[16];
  #pragma unroll
  for (int k = 0; k < 16; ++k) { accL[k] = 0.f; accH[k] = 0.f; }
  float Z = 0.f;
  const float* ph = p1 + (size_t)h * GN;
  const float* qh = q1 + (size_t)h * GN;
  const uint32_t* whu = Wh1u + (size_t)h * GN * 32 + oh * 16;
  const uint32_t* bmr = bm + (size_t)ii * WPR;
  int w0 = ch * CWW1;
  int w1 = w0 + CWW1; if (w1 > NW) w1 = NW;
  for (int w = w0; w < w1; ++w) {
    uint32_t bits = bmr[w];
    int jb = w * 32;
    #pragma unroll 4
    for (int b = 0; b < 32; ++b) {
      float pj = ph[jb + b];
      float qj = qh[jb + b];
      float wsel = (pj > ethr) ? (ci * pj) : (di * qj);
      float wv = ((bits >> b) & 1u) ? wsel : 0.f;
      Z += wv;
      const uint32_t* wr = whu + (size_t)(jb + b) * 32;
      #pragma unroll
      for (int k = 0; k < 16; ++k) {
        uint32_t u = wr[k];
        accL[k] = fmaf(wv, __uint_as_float(u << 16),          accL[k]);
        accH[k] = fmaf(wv, __uint_as_float(u & 0xFFFF0000u),  accH[k]);
      }
    }
  }
  if (!active) return;
  float* po = part1 + (((size_t)(h * NCH1 + ch) * GN) + i) * 64 + oh * 32;
  #pragma unroll
  for (int k = 0; k < 16; ++k) { po[2*k] = accL[k]; po[2*k+1] = accH[k]; }
  if (oh == 0) Zp1[(size_t)(h * NCH1 + ch) * GN + i] = Z;
}

// ---- combine L1 chunks: normalize, ELU, bf16 h1 write ----
__global__ void k_reduce1(const float* __restrict__ part1, const float* __restrict__ Zp1,
                          uint16_t* __restrict__ h1bf){
  int idx = blockIdx.x * 256 + threadIdx.x;
  if (idx >= GNH*GN*64) return;
  int o = idx & 63;
  int t = idx >> 6;
  int n = t % GN;
  int h = t / GN;
  float s = 0.f, z = 0.f;
  #pragma unroll
  for (int c = 0; c < NCH1; ++c) {
    s += part1[(((size_t)(h*NCH1 + c) * GN) + n) * 64 + o];
    z += Zp1[(size_t)(h*NCH1 + c) * GN + n];
  }
  float v = s / z;
  v = v > 0.f ? v : (expf(v) - 1.f);             // ELU
  h1bf[(size_t)n * GFIN + h*64 + o] = f2bf(v);
}

// ---- layer-2 GEMM: 4 rows per wave ----
__global__ __launch_bounds__(256) void k_gemm2(
    const uint16_t* __restrict__ h1bf, const float* __restrict__ W2f,
    const float* __restrict__ as2f, const float* __restrict__ at2f,
    uint16_t* __restrict__ Wh2bf, float* __restrict__ ss2, float* __restrict__ st2){
  int lane = threadIdx.x & 63;
  int wid  = threadIdx.x >> 6;
  int row0 = blockIdx.x * 16 + wid * 4;
  const uint32_t* xr[4];
  #pragma unroll
  for (int r = 0; r < 4; ++r) {
    int rc = row0 + r; if (rc > GN-1) rc = GN-1;
    xr[r] = (const uint32_t*)(h1bf + (size_t)rc * GFIN);
  }
  const float* W = W2f + lane;
  float acc[4];
  #pragma unroll
  for (int r = 0; r < 4; ++r) acc[r] = 0.f;
  #pragma unroll 4
  for (int fp = 0; fp < GFIN/2; ++fp) {
    float W0 = W[(2*fp)*64];
    float W1v = W[(2*fp+1)*64];
    #pragma unroll
    for (int r = 0; r < 4; ++r) {
      uint32_t u = xr[r][fp];
      acc[r] = fmaf(__uint_as_float(u << 16),         W0,  acc[r]);
      acc[r] = fmaf(__uint_as_float(u & 0xFFFF0000u), W1v, acc[r]);
    }
  }
  float av = as2f[lane], tv = at2f[lane];
  #pragma unroll
  for (int r = 0; r < 4; ++r) {
    int row = row0 + r;
    if (row >= GN) break;
    Wh2bf[(size_t)row * 64 + lane] = f2bf(acc[r]);
    float rs = av * acc[r];
    float rt = tv * acc[r];
    #pragma unroll
    for (int d = 32; d; d >>= 1) { rs += __shfl_xor(rs, d, 64); rt += __shfl_xor(rt, d, 64); }
    if (lane == 0) { ss2[row] = rs; st2[row] = rt; }
  }
}

// ---- layer-2 attention, j-chunked: thread-per-row, 40 outputs, partial accumulate ----
__global__ __launch_bounds__(256) void k_attn2(
    const uint32_t* __restrict__ bm, const uint32_t* __restrict__ Wh2u,
    const float* __restrict__ ss2, const float* __restrict__ p2,
    const float* __restrict__ q2, const float* __restrict__ m2,
    float* __restrict__ part2, float* __restrict__ Zp2){
  int i  = blockIdx.x * 256 + threadIdx.x;
  int ch = blockIdx.y;
  bool active = (i < GN);
  int ii = active ? i : 0;
  float si = ss2[ii];
  float mh = m2[0];
  float sm = si + mh;
  float M  = sm > 0.f ? sm : 0.2f * sm;
  float ci = expf(si - M);
  float di = expf(0.2f * si - M);
  float ethr = expf(-si);
  float accL[20], accH[20];
  #pragma unroll
  for (int k = 0; k < 20; ++k) { accL[k] = 0.f; accH[k] = 0.f; }
  float Z = 0.f;
  const uint32_t* bmr = bm + (size_t)ii * WPR;
  int w0 = ch * CWW2;
  int w1 = w0 + CWW2; if (w1 > NW) w1 = NW;
  for (int w = w0; w < w1; ++w) {
    uint32_t bits = bmr[w];
    int jb = w * 32;
    #pragma unroll 4
    for (int b = 0; b < 32; ++b) {
      float pj = p2[jb + b];
      float qj = q2[jb + b];
      float wsel = (pj > ethr) ? (ci * pj) : (di * qj);
      float wv = ((bits >> b) & 1u) ? wsel : 0.f;
      Z += wv;
      const uint32_t* wr = Wh2u + (size_t)(jb + b) * 32;
      #pragma unroll
      for (int k = 0; k < 20; ++k) {
        uint32_t u = wr[k];
        accL[k] = fmaf(wv, __uint_as_float(u << 16),          accL[k]);
        accH[k] = fmaf(wv, __uint_as_float(u & 0xFFFF0000u),  accH[k]);
      }
    }
  }
  if (!active) return;
  float* po = part2 + ((size_t)ch * GN + i) * 40;
  #pragma unroll
  for (int k = 0; k < 20; ++k) { po[2*k] = accL[k]; po[2*k+1] = accH[k]; }
  Zp2[(size_t)ch * GN + i] = Z;
}

// ---- combine L2 chunks: normalize, f32 logits ----
__global__ void k_reduce2(const float* __restrict__ part2, const float* __restrict__ Zp2,
                          float* __restrict__ out){
  int idx = blockIdx.x * 256 + threadIdx.x;
  if (idx >= GN * GNC) return;
  int n = idx / GNC, c = idx - n * GNC;
  float s = 0.f, z = 0.f;
  #pragma unroll 8
  for (int ch = 0; ch < NCH2; ++ch) {
    s += part2[((size_t)ch * GN + n) * 40 + c];
    z += Zp2[(size_t)ch * GN + n];
  }
  out[idx] = s / z;
}

// ---- adjacency echo (f32), written LAST over the partial scratch ----
__global__ void k_echo(const uint32_t* __restrict__ bm, float* __restrict__ echo){
  int idx = blockIdx.x * 256 + threadIdx.x;
  if (idx >= GN * WPR) return;
  int row = idx / WPR, w = idx - row * WPR;
  int j0 = w * 32;
  if (j0 >= GN) return;
  uint32_t bits = bm[idx];
  float* dst = echo + (size_t)row * GN + j0;
  int lim = GN - j0;
  if (lim >= 32) {
    float4* d4 = (float4*)dst;
    #pragma unroll
    for (int g = 0; g < 8; ++g) {
      float4 f;
      f.x = ((bits >> (4*g+0)) & 1u) ? 1.f : 0.f;
      f.y = ((bits >> (4*g+1)) & 1u) ? 1.f : 0.f;
      f.z = ((bits >> (4*g+2)) & 1u) ? 1.f : 0.f;
      f.w = ((bits >> (4*g+3)) & 1u) ? 1.f : 0.f;
      d4[g] = f;
    }
  } else {
    for (int b = 0; b < lim; ++b) dst[b] = ((bits >> b) & 1u) ? 1.f : 0.f;
  }
}

extern "C" void kernel_launch(void* const* d_in, const int* in_sizes, int n_in,
                              void* d_out, int out_size, void* d_ws, size_t ws_size,
                              hipStream_t stream){
  const float* x   = (const float*)d_in[0];
  const int*   adj = (const int*)d_in[1];
  const float* W1  = (const float*)d_in[2];
  const float* as1 = (const float*)d_in[3];
  const float* at1 = (const float*)d_in[4];
  const float* W2  = (const float*)d_in[5];
  const float* as2 = (const float*)d_in[6];
  const float* at2 = (const float*)d_in[7];
  float* out  = (float*)d_out;                    // f32 logits [6000,40]
  float* echo = out + (size_t)GN * GNC;           // f32 adjacency echo [6000,6000]
  (void)in_sizes; (void)n_in; (void)out_size; (void)ws_size;

  // chunk partials live in the echo region until k_echo overwrites it (last)
  float* part1 = echo;                                     // 8*8*6000*64  = 24.58M f32
  float* Zp1   = part1 + (size_t)GNH * NCH1 * GN * 64;     // 384K f32
  float* part2 = Zp1   + (size_t)GNH * NCH1 * GN;          // 32*6000*40   = 7.68M f32
  float* Zp2   = part2 + (size_t)NCH2 * GN * 40;           // 192K f32
  // total 32.84M f32 <= 36.0M echo capacity

  char* wsb = (char*)d_ws;
  size_t off = 0;
  auto alloc = [&](size_t bytes) -> void* {
    void* r = wsb + off;
    off = (off + bytes + 255) & ~(size_t)255;
    return r;
  };
  uint32_t* bm    = (uint32_t*)alloc((size_t)GN * WPR * 4);
  float*    W2f   = (float*)alloc((size_t)GFIN * 64 * 4);
  float*    as2f  = (float*)alloc(64 * 4);
  float*    at2f  = (float*)alloc(64 * 4);
  uint16_t* Wh1bf = (uint16_t*)alloc(((size_t)GNH * GN + 80) * 64 * 2);
  float*    ss1   = (float*)alloc((size_t)GNH * GN * 4);
  float*    st1   = (float*)alloc((size_t)GNH * GN * 4);
  float*    p1    = (float*)alloc(((size_t)GNH * GN + 128) * 4);
  float*    q1    = (float*)alloc(((size_t)GNH * GN + 128) * 4);
  float*    m1    = (float*)alloc(64);
  uint16_t* h1bf  = (uint16_t*)alloc((size_t)GN * GFIN * 2);
  uint16_t* Wh2bf = (uint16_t*)alloc(((size_t)GN + 16) * 64 * 2);
  float*    ss2   = (float*)alloc((size_t)GN * 4);
  float*    st2   = (float*)alloc((size_t)GN * 4);
  float*    p2    = (float*)alloc(((size_t)GN + 128) * 4);
  float*    q2    = (float*)alloc(((size_t)GN + 128) * 4);
  float*    m2    = (float*)alloc(64);
  // ~18.5 MB ws

  hipLaunchKernelGGL(k_prep, dim3(128), dim3(256), 0, stream,
      W2, as2, at2, W2f, as2f, at2f,
      (uint32_t*)Wh1bf, (uint32_t*)Wh2bf, p1, q1, p2, q2);
  hipLaunchKernelGGL(k_bitmask, dim3(GN*WPR/256), dim3(256), 0, stream, adj, bm);
  hipLaunchKernelGGL(k_gemm1, dim3((GN+31)/32, GNH), dim3(256), 0, stream,
      x, W1, as1, at1, Wh1bf, ss1, st1);
  hipLaunchKernelGGL(k_stats, dim3(GNH), dim3(256), 0, stream, st1, p1, q1, m1);
  hipLaunchKernelGGL(k_attn1, dim3((GN+255)/256, 2, GNH*NCH1), dim3(256), 0, stream,
      bm, (const uint32_t*)Wh1bf, ss1, p1, q1, m1, part1, Zp1);
  hipLaunchKernelGGL(k_reduce1, dim3(GNH*GN*64/256), dim3(256), 0, stream,
      part1, Zp1, h1bf);
  hipLaunchKernelGGL(k_gemm2, dim3((GN+15)/16), dim3(256), 0, stream,
      h1bf, W2f, as2f, at2f, Wh2bf, ss2, st2);
  hipLaunchKernelGGL(k_stats, dim3(1), dim3(256), 0, stream, st2, p2, q2, m2);
  hipLaunchKernelGGL(k_attn2, dim3((GN+255)/256, NCH2), dim3(256), 0, stream,
      bm, (const uint32_t*)Wh2bf, ss2, p2, q2, m2, part2, Zp2);
  hipLaunchKernelGGL(k_reduce2, dim3((GN*GNC+255)/256), dim3(256), 0, stream,
      part2, Zp2, out);
  hipLaunchKernelGGL(k_echo, dim3(GN*WPR/256), dim3(256), 0, stream, bm, echo);
}

// Round 6
// 1056.069 us; speedup vs baseline: 3.7121x; 1.3328x over previous
//
#include <hip/hip_runtime.h>
#include <hip/hip_bf16.h>
#include <stdint.h>

#define GN   6000
#define GNP  6016          // padded j-extent for Whc (188 * 32)
#define GNPW 3008          // dwords per Whc column (GNP bf16 / 2)
#define GFIN 512
#define GNH  8
#define GNC  40
#define WPR  192           // bitmask words per row
#define NW   188           // words swept (188*32 = 6016)
#define NCH2 8
#define CW2  24            // words per attn2 chunk (8*24 = 192 >= 188)

typedef __attribute__((ext_vector_type(8))) short short8v;   // 8 bf16 (4 VGPRs)
typedef __attribute__((ext_vector_type(4))) float float4v;   // MFMA accumulator

__device__ __forceinline__ uint16_t f2bf(float f){
  uint32_t u = __float_as_uint(f);
  return (uint16_t)((u + 0x7FFFu + ((u >> 16) & 1u)) >> 16);
}

// ---- prep: pad W2/a2 to 64 cols; zero p/q read-pads ----
__global__ void k_prep(const float* __restrict__ W2, const float* __restrict__ as2,
                       const float* __restrict__ at2,
                       float* __restrict__ W2f, float* __restrict__ as2f,
                       float* __restrict__ at2f,
                       float* __restrict__ p1, float* __restrict__ q1,
                       float* __restrict__ p2, float* __restrict__ q2){
  int i = blockIdx.x * 256 + threadIdx.x;
  if (i < GFIN*64) { int f = i >> 6, c = i & 63; W2f[i] = (c < GNC) ? W2[f*GNC + c] : 0.f; }
  if (i < 64) { as2f[i] = (i < GNC) ? as2[i] : 0.f; at2f[i] = (i < GNC) ? at2[i] : 0.f; }
  if (i < 128) { p1[GNH*GN + i] = 0.f; q1[GNH*GN + i] = 0.f;
                 p2[GN + i] = 0.f;     q2[GN + i] = 0.f; }
}

// ---- adjacency -> bitmask ----
__global__ void k_bitmask(const int* __restrict__ adj, uint32_t* __restrict__ bm){
  int idx = blockIdx.x * 256 + threadIdx.x;
  if (idx >= GN * WPR) return;
  int row = idx / WPR, w = idx - row * WPR;
  int j0 = w * 32;
  uint32_t bits = 0u;
  if (j0 < GN) {
    const int* a = adj + (size_t)row * GN + j0;
    int lim = GN - j0;
    if (lim >= 32) {
      const int4* a4 = (const int4*)a;
      #pragma unroll
      for (int g = 0; g < 8; ++g) {
        int4 v = a4[g];
        bits |= (v.x != 0 ? 1u : 0u) << (4*g);
        bits |= (v.y != 0 ? 1u : 0u) << (4*g + 1);
        bits |= (v.z != 0 ? 1u : 0u) << (4*g + 2);
        bits |= (v.w != 0 ? 1u : 0u) << (4*g + 3);
      }
    } else {
      for (int b = 0; b < lim; ++b) bits |= (a[b] != 0 ? 1u : 0u) << b;
    }
  }
  bm[idx] = bits;
}

// ---- layer-1 GEMM: 8 rows/wave; writes COLUMN-MAJOR Whc1 (bf16) + scores ----
__global__ __launch_bounds__(256) void k_gemm1(
    const float* __restrict__ x, const float* __restrict__ W1,
    const float* __restrict__ as1, const float* __restrict__ at1,
    uint32_t* __restrict__ Whc1u, float* __restrict__ ss1, float* __restrict__ st1){
  int lane = threadIdx.x & 63;
  int wid  = threadIdx.x >> 6;
  int h = blockIdx.y;
  int row0 = blockIdx.x * 32 + wid * 8;
  const float* W = W1 + (size_t)h * GFIN * 64 + lane;
  const float* xr[8];
  #pragma unroll
  for (int r = 0; r < 8; ++r) {
    int rc = row0 + r; if (rc > GN-1) rc = GN-1;
    xr[r] = x + (size_t)rc * GFIN;
  }
  float acc[8];
  #pragma unroll
  for (int r = 0; r < 8; ++r) acc[r] = 0.f;
  #pragma unroll 4
  for (int f = 0; f < GFIN; ++f) {
    float Wv = W[f*64];
    #pragma unroll
    for (int r = 0; r < 8; ++r) acc[r] = fmaf(xr[r][f], Wv, acc[r]);
  }
  // transposed bf16 store: column (h,o=lane), rows row0..row0+7 (16 B)
  uint32_t pk[4];
  #pragma unroll
  for (int t = 0; t < 4; ++t)
    pk[t] = (uint32_t)f2bf(acc[2*t]) | ((uint32_t)f2bf(acc[2*t+1]) << 16);
  *(uint4*)(Whc1u + ((size_t)h*64 + lane)*GNPW + (row0 >> 1)) =
      make_uint4(pk[0], pk[1], pk[2], pk[3]);
  float av = as1[h*64 + lane], tv = at1[h*64 + lane];
  #pragma unroll
  for (int r = 0; r < 8; ++r) {
    int row = row0 + r;
    if (row >= GN) break;
    float rs = av * acc[r];
    float rt = tv * acc[r];
    #pragma unroll
    for (int d = 32; d; d >>= 1) { rs += __shfl_xor(rs, d, 64); rt += __shfl_xor(rt, d, 64); }
    if (lane == 0) { ss1[(size_t)h*GN + row] = rs; st1[(size_t)h*GN + row] = rt; }
  }
}

// ---- column stats: p=exp(s), q=exp(0.2 s), m=max(s) ----
__global__ void k_stats(const float* __restrict__ s_tgt, float* __restrict__ p,
                        float* __restrict__ q, float* __restrict__ m){
  int h = blockIdx.x;
  __shared__ float red[256];
  float mx = -3.0e38f;
  for (int n = threadIdx.x; n < GN; n += 256) {
    float s = s_tgt[(size_t)h*GN + n];
    p[(size_t)h*GN + n] = expf(s);
    q[(size_t)h*GN + n] = expf(0.2f * s);
    mx = fmaxf(mx, s);
  }
  red[threadIdx.x] = mx;
  __syncthreads();
  for (int d = 128; d > 0; d >>= 1) {
    if (threadIdx.x < d) red[threadIdx.x] = fmaxf(red[threadIdx.x], red[threadIdx.x + d]);
    __syncthreads();
  }
  if (threadIdx.x == 0) m[h] = red[0];
}

// ---- layer-1 attention via MFMA: wave = 16 rows x 64 cols, K-sweep j ----
// P built in-register: wv = bit ? max(ci*pj, di*qj) : 0  (max == LR branch select)
// bf16-truncated wv used for BOTH the MFMA A-frag and Z (bias cancels in ratio).
__global__ __launch_bounds__(256) void k_attn1(
    const uint32_t* __restrict__ bm, const uint32_t* __restrict__ Whc,
    const float* __restrict__ ss1, const float* __restrict__ p1,
    const float* __restrict__ q1, const float* __restrict__ m1,
    uint16_t* __restrict__ h1bf){
  int lane = threadIdx.x & 63;
  int wid  = threadIdx.x >> 6;
  int h = blockIdx.y;
  int row0 = blockIdx.x * 64 + wid * 16;
  int g = lane >> 4;           // k-group
  int r = lane & 15;           // A row / B col within tile
  int gr = row0 + r; int grc = gr < GN-1 ? gr : GN-1;
  float si = ss1[(size_t)h*GN + grc];
  float mh = m1[h];
  float sm = si + mh;
  float M  = sm > 0.f ? sm : 0.2f * sm;
  float ci = expf(si - M);
  float di = expf(0.2f*si - M);
  const float* ph = p1 + (size_t)h * GN;
  const float* qh = q1 + (size_t)h * GN;
  const uint32_t* bmr = bm + (size_t)grc * WPR;
  const uint32_t* wc[4];
  #pragma unroll
  for (int n = 0; n < 4; ++n) wc[n] = Whc + ((size_t)h*64 + n*16 + r) * GNPW;
  float4v acc[4];
  #pragma unroll
  for (int n = 0; n < 4; ++n) acc[n] = (float4v){0.f, 0.f, 0.f, 0.f};
  float zacc = 0.f;
  for (int w = 0; w < NW; ++w) {
    int jb = w * 32;
    uint32_t bmw = bmr[w];
    uint32_t nl = (bmw >> (4*g)) & 0xFu;          // bits for j = jb+4g+0..3
    uint32_t nh = (bmw >> (16 + 4*g)) & 0xFu;     // bits for j = jb+16+4g+0..3
    float4 pl = *(const float4*)(ph + jb + 4*g);
    float4 pH = *(const float4*)(ph + jb + 16 + 4*g);
    float4 ql = *(const float4*)(qh + jb + 4*g);
    float4 qH = *(const float4*)(qh + jb + 16 + 4*g);
    float wv[8];
    wv[0] = (nl & 1u) ? fmaxf(ci*pl.x, di*ql.x) : 0.f;
    wv[1] = (nl & 2u) ? fmaxf(ci*pl.y, di*ql.y) : 0.f;
    wv[2] = (nl & 4u) ? fmaxf(ci*pl.z, di*ql.z) : 0.f;
    wv[3] = (nl & 8u) ? fmaxf(ci*pl.w, di*ql.w) : 0.f;
    wv[4] = (nh & 1u) ? fmaxf(ci*pH.x, di*qH.x) : 0.f;
    wv[5] = (nh & 2u) ? fmaxf(ci*pH.y, di*qH.y) : 0.f;
    wv[6] = (nh & 4u) ? fmaxf(ci*pH.z, di*qH.z) : 0.f;
    wv[7] = (nh & 8u) ? fmaxf(ci*pH.w, di*qH.w) : 0.f;
    union { uint32_t u4[4]; short8v s; } A;
    #pragma unroll
    for (int t = 0; t < 4; ++t) {
      uint32_t lo = __float_as_uint(wv[2*t])   & 0xFFFF0000u;
      uint32_t hi = __float_as_uint(wv[2*t+1]) & 0xFFFF0000u;
      zacc += __uint_as_float(lo) + __uint_as_float(hi);
      A.u4[t] = (lo >> 16) | hi;
    }
    #pragma unroll
    for (int n = 0; n < 4; ++n) {
      uint2 lo = *(const uint2*)(wc[n] + w*16 + 2*g);
      uint2 hi = *(const uint2*)(wc[n] + w*16 + 8 + 2*g);
      union { uint32_t u4[4]; short8v s; } B;
      B.u4[0] = lo.x; B.u4[1] = lo.y; B.u4[2] = hi.x; B.u4[3] = hi.y;
      acc[n] = __builtin_amdgcn_mfma_f32_16x16x32_bf16(A.s, B.s, acc[n], 0, 0, 0);
    }
  }
  zacc += __shfl_xor(zacc, 16, 64);
  zacc += __shfl_xor(zacc, 32, 64);          // lane l: Z for row l&15
  #pragma unroll
  for (int reg = 0; reg < 4; ++reg) {
    int rw = g*4 + reg;                       // C/D row within tile
    float Zr = __shfl(zacc, rw, 64);
    int grow = row0 + rw;
    if (grow < GN) {
      float inv = 1.f / Zr;
      #pragma unroll
      for (int n = 0; n < 4; ++n) {
        float v = acc[n][reg] * inv;
        v = v > 0.f ? v : (expf(v) - 1.f);   // ELU
        h1bf[(size_t)grow * GFIN + h*64 + n*16 + r] = f2bf(v);
      }
    }
  }
}

// ---- layer-2 GEMM: 4 rows/wave; column-major Whc2 + scores ----
__global__ __launch_bounds__(256) void k_gemm2(
    const uint16_t* __restrict__ h1bf, const float* __restrict__ W2f,
    const float* __restrict__ as2f, const float* __restrict__ at2f,
    uint32_t* __restrict__ Whc2u, float* __restrict__ ss2, float* __restrict__ st2){
  int lane = threadIdx.x & 63;
  int wid  = threadIdx.x >> 6;
  int row0 = blockIdx.x * 16 + wid * 4;
  const uint32_t* xr[4];
  #pragma unroll
  for (int r = 0; r < 4; ++r) {
    int rc = row0 + r; if (rc > GN-1) rc = GN-1;
    xr[r] = (const uint32_t*)(h1bf + (size_t)rc * GFIN);
  }
  const float* W = W2f + lane;
  float acc[4];
  #pragma unroll
  for (int r = 0; r < 4; ++r) acc[r] = 0.f;
  #pragma unroll 4
  for (int fp = 0; fp < GFIN/2; ++fp) {
    float W0 = W[(2*fp)*64];
    float W1v = W[(2*fp+1)*64];
    #pragma unroll
    for (int r = 0; r < 4; ++r) {
      uint32_t u = xr[r][fp];
      acc[r] = fmaf(__uint_as_float(u << 16),         W0,  acc[r]);
      acc[r] = fmaf(__uint_as_float(u & 0xFFFF0000u), W1v, acc[r]);
    }
  }
  uint32_t pk0 = (uint32_t)f2bf(acc[0]) | ((uint32_t)f2bf(acc[1]) << 16);
  uint32_t pk1 = (uint32_t)f2bf(acc[2]) | ((uint32_t)f2bf(acc[3]) << 16);
  *(uint2*)(Whc2u + (size_t)lane*GNPW + (row0 >> 1)) = make_uint2(pk0, pk1);
  float av = as2f[lane], tv = at2f[lane];
  #pragma unroll
  for (int r = 0; r < 4; ++r) {
    int row = row0 + r;
    if (row >= GN) break;
    float rs = av * acc[r];
    float rt = tv * acc[r];
    #pragma unroll
    for (int d = 32; d; d >>= 1) { rs += __shfl_xor(rs, d, 64); rt += __shfl_xor(rt, d, 64); }
    if (lane == 0) { ss2[row] = rs; st2[row] = rt; }
  }
}

// ---- layer-2 attention via MFMA, K-chunked; f32 partials + Z per chunk ----
__global__ __launch_bounds__(256) void k_attn2(
    const uint32_t* __restrict__ bm, const uint32_t* __restrict__ Whc2,
    const float* __restrict__ ss2, const float* __restrict__ p2,
    const float* __restrict__ q2, const float* __restrict__ m2,
    float* __restrict__ part2, float* __restrict__ Zp2){
  int lane = threadIdx.x & 63;
  int wid  = threadIdx.x >> 6;
  int ch = blockIdx.y;
  int row0 = blockIdx.x * 64 + wid * 16;
  int g = lane >> 4;
  int r = lane & 15;
  int gr = row0 + r; int grc = gr < GN-1 ? gr : GN-1;
  float si = ss2[grc];
  float mh = m2[0];
  float sm = si + mh;
  float M  = sm > 0.f ? sm : 0.2f * sm;
  float ci = expf(si - M);
  float di = expf(0.2f*si - M);
  const uint32_t* bmr = bm + (size_t)grc * WPR;
  const uint32_t* wc[4];
  #pragma unroll
  for (int n = 0; n < 4; ++n) wc[n] = Whc2 + ((size_t)n*16 + r) * GNPW;
  float4v acc[4];
  #pragma unroll
  for (int n = 0; n < 4; ++n) acc[n] = (float4v){0.f, 0.f, 0.f, 0.f};
  float zacc = 0.f;
  int w0 = ch * CW2;
  int w1 = w0 + CW2; if (w1 > NW) w1 = NW;
  for (int w = w0; w < w1; ++w) {
    int jb = w * 32;
    uint32_t bmw = bmr[w];
    uint32_t nl = (bmw >> (4*g)) & 0xFu;
    uint32_t nh = (bmw >> (16 + 4*g)) & 0xFu;
    float4 pl = *(const float4*)(p2 + jb + 4*g);
    float4 pH = *(const float4*)(p2 + jb + 16 + 4*g);
    float4 ql = *(const float4*)(q2 + jb + 4*g);
    float4 qH = *(const float4*)(q2 + jb + 16 + 4*g);
    float wv[8];
    wv[0] = (nl & 1u) ? fmaxf(ci*pl.x, di*ql.x) : 0.f;
    wv[1] = (nl & 2u) ? fmaxf(ci*pl.y, di*ql.y) : 0.f;
    wv[2] = (nl & 4u) ? fmaxf(ci*pl.z, di*ql.z) : 0.f;
    wv[3] = (nl & 8u) ? fmaxf(ci*pl.w, di*ql.w) : 0.f;
    wv[4] = (nh & 1u) ? fmaxf(ci*pH.x, di*qH.x) : 0.f;
    wv[5] = (nh & 2u) ? fmaxf(ci*pH.y, di*qH.y) : 0.f;
    wv[6] = (nh & 4u) ? fmaxf(ci*pH.z, di*qH.z) : 0.f;
    wv[7] = (nh & 8u) ? fmaxf(ci*pH.w, di*qH.w) : 0.f;
    union { uint32_t u4[4]; short8v s; } A;
    #pragma unroll
    for (int t = 0; t < 4; ++t) {
      uint32_t lo = __float_as_uint(wv[2*t])   & 0xFFFF0000u;
      uint32_t hi = __float_as_uint(wv[2*t+1]) & 0xFFFF0000u;
      zacc += __uint_as_float(lo) + __uint_as_float(hi);
      A.u4[t] = (lo >> 16) | hi;
    }
    #pragma unroll
    for (int n = 0; n < 4; ++n) {
      uint2 lo = *(const uint2*)(wc[n] + w*16 + 2*g);
      uint2 hi = *(const uint2*)(wc[n] + w*16 + 8 + 2*g);
      union { uint32_t u4[4]; short8v s; } B;
      B.u4[0] = lo.x; B.u4[1] = lo.y; B.u4[2] = hi.x; B.u4[3] = hi.y;
      acc[n] = __builtin_amdgcn_mfma_f32_16x16x32_bf16(A.s, B.s, acc[n], 0, 0, 0);
    }
  }
  zacc += __shfl_xor(zacc, 16, 64);
  zacc += __shfl_xor(zacc, 32, 64);
  #pragma unroll
  for (int reg = 0; reg < 4; ++reg) {
    int rw = g*4 + reg;
    int grow = row0 + rw;
    if (grow < GN) {
      #pragma unroll
      for (int n = 0; n < 4; ++n)
        part2[((size_t)ch * GN + grow) * 64 + n*16 + r] = acc[n][reg];
    }
  }
  if (lane < 16 && row0 + lane < GN) Zp2[(size_t)ch * GN + row0 + lane] = zacc;
}

// ---- combine L2 chunks: normalize, f32 logits ----
__global__ void k_reduce2(const float* __restrict__ part2, const float* __restrict__ Zp2,
                          float* __restrict__ out){
  int idx = blockIdx.x * 256 + threadIdx.x;
  if (idx >= GN * GNC) return;
  int n = idx / GNC, c = idx - n * GNC;
  float s = 0.f, z = 0.f;
  #pragma unroll
  for (int ch = 0; ch < NCH2; ++ch) {
    s += part2[((size_t)ch * GN + n) * 64 + c];
    z += Zp2[(size_t)ch * GN + n];
  }
  out[idx] = s / z;
}

// ---- adjacency echo (f32), written LAST over the partial scratch ----
__global__ void k_echo(const uint32_t* __restrict__ bm, float* __restrict__ echo){
  int idx = blockIdx.x * 256 + threadIdx.x;
  if (idx >= GN * WPR) return;
  int row = idx / WPR, w = idx - row * WPR;
  int j0 = w * 32;
  if (j0 >= GN) return;
  uint32_t bits = bm[idx];
  float* dst = echo + (size_t)row * GN + j0;
  int lim = GN - j0;
  if (lim >= 32) {
    float4* d4 = (float4*)dst;
    #pragma unroll
    for (int g = 0; g < 8; ++g) {
      float4 f;
      f.x = ((bits >> (4*g+0)) & 1u) ? 1.f : 0.f;
      f.y = ((bits >> (4*g+1)) & 1u) ? 1.f : 0.f;
      f.z = ((bits >> (4*g+2)) & 1u) ? 1.f : 0.f;
      f.w = ((bits >> (4*g+3)) & 1u) ? 1.f : 0.f;
      d4[g] = f;
    }
  } else {
    for (int b = 0; b < lim; ++b) dst[b] = ((bits >> b) & 1u) ? 1.f : 0.f;
  }
}

extern "C" void kernel_launch(void* const* d_in, const int* in_sizes, int n_in,
                              void* d_out, int out_size, void* d_ws, size_t ws_size,
                              hipStream_t stream){
  const float* x   = (const float*)d_in[0];
  const int*   adj = (const int*)d_in[1];
  const float* W1  = (const float*)d_in[2];
  const float* as1 = (const float*)d_in[3];
  const float* at1 = (const float*)d_in[4];
  const float* W2  = (const float*)d_in[5];
  const float* as2 = (const float*)d_in[6];
  const float* at2 = (const float*)d_in[7];
  float* out  = (float*)d_out;                    // f32 logits [6000,40]
  float* echo = out + (size_t)GN * GNC;           // f32 adjacency echo [6000,6000]
  (void)in_sizes; (void)n_in; (void)out_size; (void)ws_size;

  // attn2 chunk partials live in the echo region until k_echo overwrites it
  float* part2 = echo;                            // 8*6000*64 = 3.07M f32
  float* Zp2   = part2 + (size_t)NCH2 * GN * 64;  // 48K f32

  char* wsb = (char*)d_ws;
  size_t off = 0;
  auto alloc = [&](size_t bytes) -> void* {
    void* r = wsb + off;
    off = (off + bytes + 255) & ~(size_t)255;
    return r;
  };
  uint32_t* bm    = (uint32_t*)alloc((size_t)GN * WPR * 4);
  float*    W2f   = (float*)alloc((size_t)GFIN * 64 * 4);
  float*    as2f  = (float*)alloc(64 * 4);
  float*    at2f  = (float*)alloc(64 * 4);
  uint32_t* Whc1u = (uint32_t*)alloc((size_t)GNH * 64 * GNPW * 4);  // col-major bf16 [h][o][j]
  uint32_t* Whc2u = (uint32_t*)alloc((size_t)64 * GNPW * 4);        // col-major bf16 [o][j]
  float*    ss1   = (float*)alloc((size_t)GNH * GN * 4);
  float*    st1   = (float*)alloc((size_t)GNH * GN * 4);
  float*    p1    = (float*)alloc(((size_t)GNH * GN + 128) * 4);
  float*    q1    = (float*)alloc(((size_t)GNH * GN + 128) * 4);
  float*    m1    = (float*)alloc(64);
  uint16_t* h1bf  = (uint16_t*)alloc((size_t)GN * GFIN * 2);
  float*    ss2   = (float*)alloc((size_t)GN * 4);
  float*    st2   = (float*)alloc((size_t)GN * 4);
  float*    p2    = (float*)alloc(((size_t)GN + 128) * 4);
  float*    q2    = (float*)alloc(((size_t)GN + 128) * 4);
  float*    m2    = (float*)alloc(64);
  // ~20 MB ws

  hipLaunchKernelGGL(k_prep, dim3(128), dim3(256), 0, stream,
      W2, as2, at2, W2f, as2f, at2f, p1, q1, p2, q2);
  hipLaunchKernelGGL(k_bitmask, dim3(GN*WPR/256), dim3(256), 0, stream, adj, bm);
  hipLaunchKernelGGL(k_gemm1, dim3((GN+31)/32, GNH), dim3(256), 0, stream,
      x, W1, as1, at1, Whc1u, ss1, st1);
  hipLaunchKernelGGL(k_stats, dim3(GNH), dim3(256), 0, stream, st1, p1, q1, m1);
  hipLaunchKernelGGL(k_attn1, dim3((GN+63)/64, GNH), dim3(256), 0, stream,
      bm, Whc1u, ss1, p1, q1, m1, h1bf);
  hipLaunchKernelGGL(k_gemm2, dim3((GN+15)/16), dim3(256), 0, stream,
      h1bf, W2f, as2f, at2f, Whc2u, ss2, st2);
  hipLaunchKernelGGL(k_stats, dim3(1), dim3(256), 0, stream, st2, p2, q2, m2);
  hipLaunchKernelGGL(k_attn2, dim3((GN+63)/64, NCH2), dim3(256), 0, stream,
      bm, Whc2u, ss2, p2, q2, m2, part2, Zp2);
  hipLaunchKernelGGL(k_reduce2, dim3((GN*GNC+255)/256), dim3(256), 0, stream,
      part2, Zp2, out);
  hipLaunchKernelGGL(k_echo, dim3(GN*WPR/256), dim3(256), 0, stream, bm, echo);
}

// Round 7
// 710.283 us; speedup vs baseline: 5.5193x; 1.4868x over previous
//
#include <hip/hip_runtime.h>
#include <hip/hip_bf16.h>
#include <stdint.h>

#define GN   6000
#define GFIN 512
#define GNH  8
#define GNC  40
#define WPR  192           // bitmask words per row (192*32 = 6144)
#define NT   192           // j-tiles per head (tiles 188..191 are zero pads)
#define PQS  6144          // per-head stride of p/q (zero-padded tail)
#define KC1  4             // attn1 K-chunks (48 w each)
#define CW1  48
#define KC2  24            // attn2 K-chunks (8 w each)
#define CW2  8

typedef __attribute__((ext_vector_type(8))) short short8v;   // 8 bf16
typedef __attribute__((ext_vector_type(4))) float float4v;   // MFMA acc

__device__ __forceinline__ uint16_t f2bf(float f){
  uint32_t u = __float_as_uint(f);
  return (uint16_t)((u + 0x7FFFu + ((u >> 16) & 1u)) >> 16);
}

// ---- prep: pad W2/a2; zero p/q pads and zero pad-tiles of Whc ----
__global__ void k_prep(const float* __restrict__ W2, const float* __restrict__ as2,
                       const float* __restrict__ at2,
                       float* __restrict__ W2f, float* __restrict__ as2f,
                       float* __restrict__ at2f,
                       uint32_t* __restrict__ Wt1, uint32_t* __restrict__ Wt2,
                       float* __restrict__ p1, float* __restrict__ q1,
                       float* __restrict__ p2, float* __restrict__ q2){
  int i = blockIdx.x * 256 + threadIdx.x;
  if (i < GFIN*64) { int f = i >> 6, c = i & 63; W2f[i] = (c < GNC) ? W2[f*GNC + c] : 0.f; }
  if (i < 64) { as2f[i] = (i < GNC) ? as2[i] : 0.f; at2f[i] = (i < GNC) ? at2[i] : 0.f; }
  if (i < GNH*PQS) { p1[i] = 0.f; q1[i] = 0.f; }
  if (i < PQS) { p2[i] = 0.f; q2[i] = 0.f; }
  if (i < 37*1024) {                     // zero pad tiles: Wt1 h*4 tiles 188..191; Wt2 tiles 187..191
    int t = i >> 10, d = i & 1023;
    if (t < 32) Wt1[((size_t)(t >> 2) * NT + 188 + (t & 3)) * 1024 + d] = 0u;
    else        Wt2[((size_t)(187 + (t - 32))) * 1024 + d] = 0u;
  }
}

// ---- adjacency -> bitmask ----
__global__ void k_bitmask(const int* __restrict__ adj, uint32_t* __restrict__ bm){
  int idx = blockIdx.x * 256 + threadIdx.x;
  if (idx >= GN * WPR) return;
  int row = idx / WPR, w = idx - row * WPR;
  int j0 = w * 32;
  uint32_t bits = 0u;
  if (j0 < GN) {
    const int* a = adj + (size_t)row * GN + j0;
    int lim = GN - j0;
    if (lim >= 32) {
      const int4* a4 = (const int4*)a;
      #pragma unroll
      for (int g = 0; g < 8; ++g) {
        int4 v = a4[g];
        bits |= (v.x != 0 ? 1u : 0u) << (4*g);
        bits |= (v.y != 0 ? 1u : 0u) << (4*g + 1);
        bits |= (v.z != 0 ? 1u : 0u) << (4*g + 2);
        bits |= (v.w != 0 ? 1u : 0u) << (4*g + 3);
      }
    } else {
      for (int b = 0; b < lim; ++b) bits |= (a[b] != 0 ? 1u : 0u) << b;
    }
  }
  bm[idx] = bits;
}

// ---- layer-1 GEMM: 8 rows/wave; writes TILED bf16 Whc + scores ----
// tile layout (4KB): dword index c*16 + d', where B-frag lane (g,r) reads
// d' 4g..4g+3 == global j-pair dwords {2g,2g+1,8+2g,8+2g+1}
__global__ __launch_bounds__(256) void k_gemm1(
    const float* __restrict__ x, const float* __restrict__ W1,
    const float* __restrict__ as1, const float* __restrict__ at1,
    uint32_t* __restrict__ Wt1, float* __restrict__ ss1, float* __restrict__ st1){
  int lane = threadIdx.x & 63;
  int wid  = threadIdx.x >> 6;
  int h = blockIdx.y;
  int row0 = blockIdx.x * 32 + wid * 8;
  const float* W = W1 + (size_t)h * GFIN * 64 + lane;
  const float* xr[8];
  #pragma unroll
  for (int r = 0; r < 8; ++r) {
    int rc = row0 + r; if (rc > GN-1) rc = GN-1;
    xr[r] = x + (size_t)rc * GFIN;
  }
  float acc[8];
  #pragma unroll
  for (int r = 0; r < 8; ++r) acc[r] = 0.f;
  #pragma unroll 4
  for (int f = 0; f < GFIN; ++f) {
    float Wv = W[f*64];
    #pragma unroll
    for (int r = 0; r < 8; ++r) acc[r] = fmaf(xr[r][f], Wv, acc[r]);
  }
  uint32_t pk[4];
  #pragma unroll
  for (int t = 0; t < 4; ++t)
    pk[t] = (uint32_t)f2bf(acc[2*t]) | ((uint32_t)f2bf(acc[2*t+1]) << 16);
  int tw = row0 >> 5;
  int qq = (row0 >> 3) & 3;
  int d0 = ((qq & 1) << 3) | ((qq >> 1) << 1);       // 0,8,2,10
  uint32_t* tb = Wt1 + ((size_t)h * NT + tw) * 1024 + lane * 16 + d0;
  *(uint2*)(tb)     = make_uint2(pk[0], pk[1]);
  *(uint2*)(tb + 4) = make_uint2(pk[2], pk[3]);
  float av = as1[h*64 + lane], tv = at1[h*64 + lane];
  #pragma unroll
  for (int r = 0; r < 8; ++r) {
    int row = row0 + r;
    if (row >= GN) break;
    float rs = av * acc[r];
    float rt = tv * acc[r];
    #pragma unroll
    for (int d = 32; d; d >>= 1) { rs += __shfl_xor(rs, d, 64); rt += __shfl_xor(rt, d, 64); }
    if (lane == 0) { ss1[(size_t)h*GN + row] = rs; st1[(size_t)h*GN + row] = rt; }
  }
}

// ---- column stats: p=exp(s), q=exp(0.2 s) (stride PQS), m=max(s) ----
__global__ void k_stats(const float* __restrict__ s_tgt, float* __restrict__ p,
                        float* __restrict__ q, float* __restrict__ m){
  int h = blockIdx.x;
  __shared__ float red[256];
  float mx = -3.0e38f;
  for (int n = threadIdx.x; n < GN; n += 256) {
    float s = s_tgt[(size_t)h*GN + n];
    p[(size_t)h*PQS + n] = expf(s);
    q[(size_t)h*PQS + n] = expf(0.2f * s);
    mx = fmaxf(mx, s);
  }
  red[threadIdx.x] = mx;
  __syncthreads();
  for (int d = 128; d > 0; d >>= 1) {
    if (threadIdx.x < d) red[threadIdx.x] = fmaxf(red[threadIdx.x], red[threadIdx.x + d]);
    __syncthreads();
  }
  if (threadIdx.x == 0) m[h] = red[0];
}

__device__ __forceinline__ void build_A(uint32_t bw, int g, float ci, float di,
    const float4& pl, const float4& pH, const float4& ql, const float4& qH,
    uint32_t A[4], float& z){
  uint32_t nl = (bw >> (4*g)) & 0xFu;
  uint32_t nh = (bw >> (16 + 4*g)) & 0xFu;
  float wv[8];
  wv[0] = (nl & 1u) ? fmaxf(ci*pl.x, di*ql.x) : 0.f;
  wv[1] = (nl & 2u) ? fmaxf(ci*pl.y, di*ql.y) : 0.f;
  wv[2] = (nl & 4u) ? fmaxf(ci*pl.z, di*ql.z) : 0.f;
  wv[3] = (nl & 8u) ? fmaxf(ci*pl.w, di*ql.w) : 0.f;
  wv[4] = (nh & 1u) ? fmaxf(ci*pH.x, di*qH.x) : 0.f;
  wv[5] = (nh & 2u) ? fmaxf(ci*pH.y, di*qH.y) : 0.f;
  wv[6] = (nh & 4u) ? fmaxf(ci*pH.z, di*qH.z) : 0.f;
  wv[7] = (nh & 8u) ? fmaxf(ci*pH.w, di*qH.w) : 0.f;
  #pragma unroll
  for (int t = 0; t < 4; ++t) {
    uint32_t lo = __float_as_uint(wv[2*t])   & 0xFFFF0000u;
    uint32_t hi = __float_as_uint(wv[2*t+1]) & 0xFFFF0000u;
    z += __uint_as_float(lo) + __uint_as_float(hi);
    A[t] = (lo >> 16) | hi;
  }
}

// ---- unified attention kernel: 32 rows/wave, tiled-B coalesced loads,
//      K-chunked partial accumulate. wv = bit ? max(ci*pj, di*qj) : 0 ----
template<int CW>
__global__ __launch_bounds__(256, 4) void k_attn_t(
    const uint32_t* __restrict__ bm, const uint32_t* __restrict__ Wt,
    const float* __restrict__ ss, const float* __restrict__ p,
    const float* __restrict__ q, const float* __restrict__ m,
    float* __restrict__ part, float* __restrict__ Zp){
  int lane = threadIdx.x & 63;
  int wid  = threadIdx.x >> 6;
  int h  = blockIdx.y;
  int ch = blockIdx.z;
  int row0 = blockIdx.x * 128 + wid * 32;
  int g = lane >> 4, r = lane & 15;
  int ra = row0 + r, rb = ra + 16;
  int rac = ra < GN-1 ? ra : GN-1;
  int rbc = rb < GN-1 ? rb : GN-1;
  float mh = m[h];
  float sia = ss[(size_t)h*GN + rac];
  float sib = ss[(size_t)h*GN + rbc];
  float sma = sia + mh, smb = sib + mh;
  float Ma = sma > 0.f ? sma : 0.2f * sma;
  float Mb = smb > 0.f ? smb : 0.2f * smb;
  float cia = expf(sia - Ma), dia = expf(0.2f*sia - Ma);
  float cib = expf(sib - Mb), dib = expf(0.2f*sib - Mb);
  const float* ph = p + (size_t)h * PQS;
  const float* qh = q + (size_t)h * PQS;
  const uint32_t* bma = bm + (size_t)rac * WPR;
  const uint32_t* bmb = bm + (size_t)rbc * WPR;
  const uint32_t* wt = Wt + (size_t)h * NT * 1024;
  float4v accA[4], accB[4];
  #pragma unroll
  for (int n = 0; n < 4; ++n) { accA[n] = (float4v){0,0,0,0}; accB[n] = (float4v){0,0,0,0}; }
  float za = 0.f, zb = 0.f;
  const int w0 = ch * CW;
  for (int wb = 0; wb < CW/4; ++wb) {
    uint4 b4a = *(const uint4*)(bma + w0 + wb*4);
    uint4 b4b = *(const uint4*)(bmb + w0 + wb*4);
    uint32_t ba[4] = {b4a.x, b4a.y, b4a.z, b4a.w};
    uint32_t bb[4] = {b4b.x, b4b.y, b4b.z, b4b.w};
    #pragma unroll
    for (int e = 0; e < 4; ++e) {
      int w = w0 + wb*4 + e;
      int jb = w * 32;
      float4 pl = *(const float4*)(ph + jb + 4*g);
      float4 pH = *(const float4*)(ph + jb + 16 + 4*g);
      float4 ql = *(const float4*)(qh + jb + 4*g);
      float4 qH = *(const float4*)(qh + jb + 16 + 4*g);
      union { uint32_t u4[4]; short8v s; } Aa, Ab;
      build_A(ba[e], g, cia, dia, pl, pH, ql, qH, Aa.u4, za);
      build_A(bb[e], g, cib, dib, pl, pH, ql, qH, Ab.u4, zb);
      const uint32_t* tb = wt + (size_t)w * 1024 + r*16 + g*4;
      #pragma unroll
      for (int n = 0; n < 4; ++n) {
        union { uint32_t u4[4]; short8v s; } B;
        *(uint4*)B.u4 = *(const uint4*)(tb + n*256);
        accA[n] = __builtin_amdgcn_mfma_f32_16x16x32_bf16(Aa.s, B.s, accA[n], 0, 0, 0);
        accB[n] = __builtin_amdgcn_mfma_f32_16x16x32_bf16(Ab.s, B.s, accB[n], 0, 0, 0);
      }
    }
  }
  za += __shfl_xor(za, 16, 64); za += __shfl_xor(za, 32, 64);
  zb += __shfl_xor(zb, 16, 64); zb += __shfl_xor(zb, 32, 64);
  size_t pbase = ((size_t)ch * gridDim.y + h) * GN;
  #pragma unroll
  for (int reg = 0; reg < 4; ++reg) {
    int rwa = row0 + g*4 + reg;
    int rwb = rwa + 16;
    if (rwa < GN) {
      #pragma unroll
      for (int n = 0; n < 4; ++n) part[(pbase + rwa)*64 + n*16 + r] = accA[n][reg];
    }
    if (rwb < GN) {
      #pragma unroll
      for (int n = 0; n < 4; ++n) part[(pbase + rwb)*64 + n*16 + r] = accB[n][reg];
    }
  }
  if (lane < 16) {
    if (row0 + lane < GN)      Zp[pbase + row0 + lane]      = za;
    if (row0 + 16 + lane < GN) Zp[pbase + row0 + 16 + lane] = zb;
  }
}

// ---- combine L1 chunks: normalize, ELU, bf16 h1 ----
__global__ void k_reduce1(const float* __restrict__ part1, const float* __restrict__ Zp1,
                          uint16_t* __restrict__ h1bf){
  int idx = blockIdx.x * 256 + threadIdx.x;
  if (idx >= GNH*GN*64) return;
  int o = idx & 63;
  int t = idx >> 6;
  int n = t % GN;
  int h = t / GN;
  float s = 0.f, z = 0.f;
  #pragma unroll
  for (int c = 0; c < KC1; ++c) {
    s += part1[(((size_t)c*GNH + h)*GN + n)*64 + o];
    z += Zp1[((size_t)c*GNH + h)*GN + n];
  }
  float v = s / z;
  v = v > 0.f ? v : (expf(v) - 1.f);
  h1bf[(size_t)n * GFIN + h*64 + o] = f2bf(v);
}

// ---- layer-2 GEMM: 4 rows/wave; tiled Whc2 + scores ----
__global__ __launch_bounds__(256) void k_gemm2(
    const uint16_t* __restrict__ h1bf, const float* __restrict__ W2f,
    const float* __restrict__ as2f, const float* __restrict__ at2f,
    uint32_t* __restrict__ Wt2, float* __restrict__ ss2, float* __restrict__ st2){
  int lane = threadIdx.x & 63;
  int wid  = threadIdx.x >> 6;
  int row0 = blockIdx.x * 16 + wid * 4;
  const uint32_t* xr[4];
  #pragma unroll
  for (int r = 0; r < 4; ++r) {
    int rc = row0 + r; if (rc > GN-1) rc = GN-1;
    xr[r] = (const uint32_t*)(h1bf + (size_t)rc * GFIN);
  }
  const float* W = W2f + lane;
  float acc[4];
  #pragma unroll
  for (int r = 0; r < 4; ++r) acc[r] = 0.f;
  #pragma unroll 4
  for (int fp = 0; fp < GFIN/2; ++fp) {
    float W0 = W[(2*fp)*64];
    float W1v = W[(2*fp+1)*64];
    #pragma unroll
    for (int r = 0; r < 4; ++r) {
      uint32_t u = xr[r][fp];
      acc[r] = fmaf(__uint_as_float(u << 16),         W0,  acc[r]);
      acc[r] = fmaf(__uint_as_float(u & 0xFFFF0000u), W1v, acc[r]);
    }
  }
  uint32_t pk0 = (uint32_t)f2bf(acc[0]) | ((uint32_t)f2bf(acc[1]) << 16);
  uint32_t pk1 = (uint32_t)f2bf(acc[2]) | ((uint32_t)f2bf(acc[3]) << 16);
  int tw = row0 >> 5;
  int mm = (row0 >> 2) & 7;
  int d0 = ((mm & 3) << 2) | ((mm >> 2) << 1);     // 0,4,8,12,2,6,10,14
  *(uint2*)(Wt2 + (size_t)tw*1024 + lane*16 + d0) = make_uint2(pk0, pk1);
  float av = as2f[lane], tv = at2f[lane];
  #pragma unroll
  for (int r = 0; r < 4; ++r) {
    int row = row0 + r;
    if (row >= GN) break;
    float rs = av * acc[r];
    float rt = tv * acc[r];
    #pragma unroll
    for (int d = 32; d; d >>= 1) { rs += __shfl_xor(rs, d, 64); rt += __shfl_xor(rt, d, 64); }
    if (lane == 0) { ss2[row] = rs; st2[row] = rt; }
  }
}

// ---- combine L2 chunks: normalize, f32 logits ----
__global__ void k_reduce2(const float* __restrict__ part2, const float* __restrict__ Zp2,
                          float* __restrict__ out){
  int idx = blockIdx.x * 256 + threadIdx.x;
  if (idx >= GN * GNC) return;
  int n = idx / GNC, c = idx - n * GNC;
  float s = 0.f, z = 0.f;
  #pragma unroll 8
  for (int ch = 0; ch < KC2; ++ch) {
    s += part2[((size_t)ch * GN + n) * 64 + c];
    z += Zp2[(size_t)ch * GN + n];
  }
  out[idx] = s / z;
}

// ---- adjacency echo (f32), written LAST over partial scratch ----
__global__ void k_echo(const uint32_t* __restrict__ bm, float* __restrict__ echo){
  int idx = blockIdx.x * 256 + threadIdx.x;
  if (idx >= GN * WPR) return;
  int row = idx / WPR, w = idx - row * WPR;
  int j0 = w * 32;
  if (j0 >= GN) return;
  uint32_t bits = bm[idx];
  float* dst = echo + (size_t)row * GN + j0;
  int lim = GN - j0;
  if (lim >= 32) {
    float4* d4 = (float4*)dst;
    #pragma unroll
    for (int g = 0; g < 8; ++g) {
      float4 f;
      f.x = ((bits >> (4*g+0)) & 1u) ? 1.f : 0.f;
      f.y = ((bits >> (4*g+1)) & 1u) ? 1.f : 0.f;
      f.z = ((bits >> (4*g+2)) & 1u) ? 1.f : 0.f;
      f.w = ((bits >> (4*g+3)) & 1u) ? 1.f : 0.f;
      d4[g] = f;
    }
  } else {
    for (int b = 0; b < lim; ++b) dst[b] = ((bits >> b) & 1u) ? 1.f : 0.f;
  }
}

extern "C" void kernel_launch(void* const* d_in, const int* in_sizes, int n_in,
                              void* d_out, int out_size, void* d_ws, size_t ws_size,
                              hipStream_t stream){
  const float* x   = (const float*)d_in[0];
  const int*   adj = (const int*)d_in[1];
  const float* W1  = (const float*)d_in[2];
  const float* as1 = (const float*)d_in[3];
  const float* at1 = (const float*)d_in[4];
  const float* W2  = (const float*)d_in[5];
  const float* as2 = (const float*)d_in[6];
  const float* at2 = (const float*)d_in[7];
  float* out  = (float*)d_out;                    // f32 logits [6000,40]
  float* echo = out + (size_t)GN * GNC;           // f32 adj echo [6000,6000]
  (void)in_sizes; (void)n_in; (void)out_size; (void)ws_size;

  // chunk partials live in echo region until k_echo overwrites it (last)
  float* part1 = echo;                                  // 4*8*6000*64 = 12.29M f32
  float* Zp1   = part1 + (size_t)KC1 * GNH * GN * 64;   // 192K f32
  float* part2 = Zp1   + (size_t)KC1 * GNH * GN;        // 24*6000*64 = 9.22M f32
  float* Zp2   = part2 + (size_t)KC2 * GN * 64;         // 144K f32
  // total ~21.8M f32 = 87 MB <= 144 MB echo

  char* wsb = (char*)d_ws;
  size_t off = 0;
  auto alloc = [&](size_t bytes) -> void* {
    void* r = wsb + off;
    off = (off + bytes + 255) & ~(size_t)255;
    return r;
  };
  uint32_t* bm   = (uint32_t*)alloc((size_t)GN * WPR * 4);
  float*    W2f  = (float*)alloc((size_t)GFIN * 64 * 4);
  float*    as2f = (float*)alloc(64 * 4);
  float*    at2f = (float*)alloc(64 * 4);
  uint32_t* Wt1  = (uint32_t*)alloc((size_t)GNH * NT * 1024 * 4);  // tiled bf16 Wh1
  uint32_t* Wt2  = (uint32_t*)alloc((size_t)NT * 1024 * 4);        // tiled bf16 Wh2
  float*    ss1  = (float*)alloc((size_t)GNH * GN * 4);
  float*    st1  = (float*)alloc((size_t)GNH * GN * 4);
  float*    p1   = (float*)alloc((size_t)GNH * PQS * 4);
  float*    q1   = (float*)alloc((size_t)GNH * PQS * 4);
  float*    m1   = (float*)alloc(64);
  uint16_t* h1bf = (uint16_t*)alloc((size_t)GN * GFIN * 2);
  float*    ss2  = (float*)alloc((size_t)GN * 4);
  float*    st2  = (float*)alloc((size_t)GN * 4);
  float*    p2   = (float*)alloc((size_t)PQS * 4);
  float*    q2   = (float*)alloc((size_t)PQS * 4);
  float*    m2   = (float*)alloc(64);
  // ~20 MB ws

  hipLaunchKernelGGL(k_prep, dim3(192), dim3(256), 0, stream,
      W2, as2, at2, W2f, as2f, at2f, Wt1, Wt2, p1, q1, p2, q2);
  hipLaunchKernelGGL(k_bitmask, dim3(GN*WPR/256), dim3(256), 0, stream, adj, bm);
  hipLaunchKernelGGL(k_gemm1, dim3((GN+31)/32, GNH), dim3(256), 0, stream,
      x, W1, as1, at1, Wt1, ss1, st1);
  hipLaunchKernelGGL(k_stats, dim3(GNH), dim3(256), 0, stream, st1, p1, q1, m1);
  hipLaunchKernelGGL((k_attn_t<CW1>), dim3((GN+127)/128, GNH, KC1), dim3(256), 0, stream,
      bm, Wt1, ss1, p1, q1, m1, part1, Zp1);
  hipLaunchKernelGGL(k_reduce1, dim3(GNH*GN*64/256), dim3(256), 0, stream,
      part1, Zp1, h1bf);
  hipLaunchKernelGGL(k_gemm2, dim3((GN+15)/16), dim3(256), 0, stream,
      h1bf, W2f, as2f, at2f, Wt2, ss2, st2);
  hipLaunchKernelGGL(k_stats, dim3(1), dim3(256), 0, stream, st2, p2, q2, m2);
  hipLaunchKernelGGL((k_attn_t<CW2>), dim3((GN+127)/128, 1, KC2), dim3(256), 0, stream,
      bm, Wt2, ss2, p2, q2, m2, part2, Zp2);
  hipLaunchKernelGGL(k_reduce2, dim3((GN*GNC+255)/256), dim3(256), 0, stream,
      part2, Zp2, out);
  hipLaunchKernelGGL(k_echo, dim3(GN*WPR/256), dim3(256), 0, stream, bm, echo);
}

// Round 8
// 622.738 us; speedup vs baseline: 6.2952x; 1.1406x over previous
//
#include <hip/hip_runtime.h>
#include <hip/hip_bf16.h>
#include <stdint.h>

#define GN   6000
#define GFIN 512
#define GNH  8
#define GNC  40
#define WPR  192           // bitmask words per row (192*32 = 6144)
#define NT   192           // j-tiles per head (tiles 188..191 are zero pads)
#define PQS  6144          // per-head stride of p/q (zero-padded tail)
#define KC1  4             // attn1 K-chunks (48 w each)
#define CW1  48
#define KC2  24            // attn2 K-chunks (8 w each)
#define CW2  8

typedef __attribute__((ext_vector_type(8))) short short8v;   // 8 bf16
typedef __attribute__((ext_vector_type(4))) float float4v;   // MFMA acc

__device__ __forceinline__ uint16_t f2bf(float f){
  uint32_t u = __float_as_uint(f);
  return (uint16_t)((u + 0x7FFFu + ((u >> 16) & 1u)) >> 16);
}

// ---- prep: pad W2/a2; zero p/q pads and zero pad-tiles of Whc ----
__global__ void k_prep(const float* __restrict__ W2, const float* __restrict__ as2,
                       const float* __restrict__ at2,
                       float* __restrict__ W2f, float* __restrict__ as2f,
                       float* __restrict__ at2f,
                       uint32_t* __restrict__ Wt1, uint32_t* __restrict__ Wt2,
                       float* __restrict__ p1, float* __restrict__ q1,
                       float* __restrict__ p2, float* __restrict__ q2){
  int i = blockIdx.x * 256 + threadIdx.x;
  if (i < GFIN*64) { int f = i >> 6, c = i & 63; W2f[i] = (c < GNC) ? W2[f*GNC + c] : 0.f; }
  if (i < 64) { as2f[i] = (i < GNC) ? as2[i] : 0.f; at2f[i] = (i < GNC) ? at2[i] : 0.f; }
  if (i < GNH*PQS) { p1[i] = 0.f; q1[i] = 0.f; }
  if (i < PQS) { p2[i] = 0.f; q2[i] = 0.f; }
  if (i < 37*1024) {                     // zero pad tiles: Wt1 h*4 tiles 188..191; Wt2 tiles 187..191
    int t = i >> 10, d = i & 1023;
    if (t < 32) Wt1[((size_t)(t >> 2) * NT + 188 + (t & 3)) * 1024 + d] = 0u;
    else        Wt2[((size_t)(187 + (t - 32))) * 1024 + d] = 0u;
  }
}

// ---- adjacency -> bitmask ----
__global__ void k_bitmask(const int* __restrict__ adj, uint32_t* __restrict__ bm){
  int idx = blockIdx.x * 256 + threadIdx.x;
  if (idx >= GN * WPR) return;
  int row = idx / WPR, w = idx - row * WPR;
  int j0 = w * 32;
  uint32_t bits = 0u;
  if (j0 < GN) {
    const int* a = adj + (size_t)row * GN + j0;
    int lim = GN - j0;
    if (lim >= 32) {
      const int4* a4 = (const int4*)a;
      #pragma unroll
      for (int g = 0; g < 8; ++g) {
        int4 v = a4[g];
        bits |= (v.x != 0 ? 1u : 0u) << (4*g);
        bits |= (v.y != 0 ? 1u : 0u) << (4*g + 1);
        bits |= (v.z != 0 ? 1u : 0u) << (4*g + 2);
        bits |= (v.w != 0 ? 1u : 0u) << (4*g + 3);
      }
    } else {
      for (int b = 0; b < lim; ++b) bits |= (a[b] != 0 ? 1u : 0u) << b;
    }
  }
  bm[idx] = bits;
}

// ---- layer-1 GEMM: 8 rows/wave; writes TILED bf16 Whc + scores ----
__global__ __launch_bounds__(256) void k_gemm1(
    const float* __restrict__ x, const float* __restrict__ W1,
    const float* __restrict__ as1, const float* __restrict__ at1,
    uint32_t* __restrict__ Wt1, float* __restrict__ ss1, float* __restrict__ st1){
  int lane = threadIdx.x & 63;
  int wid  = threadIdx.x >> 6;
  int h = blockIdx.y;
  int row0 = blockIdx.x * 32 + wid * 8;
  const float* W = W1 + (size_t)h * GFIN * 64 + lane;
  const float* xr[8];
  #pragma unroll
  for (int r = 0; r < 8; ++r) {
    int rc = row0 + r; if (rc > GN-1) rc = GN-1;
    xr[r] = x + (size_t)rc * GFIN;
  }
  float acc[8];
  #pragma unroll
  for (int r = 0; r < 8; ++r) acc[r] = 0.f;
  #pragma unroll 4
  for (int f = 0; f < GFIN; ++f) {
    float Wv = W[f*64];
    #pragma unroll
    for (int r = 0; r < 8; ++r) acc[r] = fmaf(xr[r][f], Wv, acc[r]);
  }
  uint32_t pk[4];
  #pragma unroll
  for (int t = 0; t < 4; ++t)
    pk[t] = (uint32_t)f2bf(acc[2*t]) | ((uint32_t)f2bf(acc[2*t+1]) << 16);
  int tw = row0 >> 5;
  int qq = (row0 >> 3) & 3;
  int d0 = ((qq & 1) << 3) | ((qq >> 1) << 1);       // 0,8,2,10
  uint32_t* tb = Wt1 + ((size_t)h * NT + tw) * 1024 + lane * 16 + d0;
  *(uint2*)(tb)     = make_uint2(pk[0], pk[1]);
  *(uint2*)(tb + 4) = make_uint2(pk[2], pk[3]);
  float av = as1[h*64 + lane], tv = at1[h*64 + lane];
  #pragma unroll
  for (int r = 0; r < 8; ++r) {
    int row = row0 + r;
    if (row >= GN) break;
    float rs = av * acc[r];
    float rt = tv * acc[r];
    #pragma unroll
    for (int d = 32; d; d >>= 1) { rs += __shfl_xor(rs, d, 64); rt += __shfl_xor(rt, d, 64); }
    if (lane == 0) { ss1[(size_t)h*GN + row] = rs; st1[(size_t)h*GN + row] = rt; }
  }
}

// ---- column stats: p=exp(s), q=exp(0.2 s) (stride PQS), m=max(s) ----
__global__ void k_stats(const float* __restrict__ s_tgt, float* __restrict__ p,
                        float* __restrict__ q, float* __restrict__ m){
  int h = blockIdx.x;
  __shared__ float red[256];
  float mx = -3.0e38f;
  for (int n = threadIdx.x; n < GN; n += 256) {
    float s = s_tgt[(size_t)h*GN + n];
    p[(size_t)h*PQS + n] = expf(s);
    q[(size_t)h*PQS + n] = expf(0.2f * s);
    mx = fmaxf(mx, s);
  }
  red[threadIdx.x] = mx;
  __syncthreads();
  for (int d = 128; d > 0; d >>= 1) {
    if (threadIdx.x < d) red[threadIdx.x] = fmaxf(red[threadIdx.x], red[threadIdx.x + d]);
    __syncthreads();
  }
  if (threadIdx.x == 0) m[h] = red[0];
}

__device__ __forceinline__ void build_A(uint32_t bw, int g, float ci, float di,
    const float4& pl, const float4& pH, const float4& ql, const float4& qH,
    uint32_t A[4], float& z){
  uint32_t nl = (bw >> (4*g)) & 0xFu;
  uint32_t nh = (bw >> (16 + 4*g)) & 0xFu;
  float wv[8];
  wv[0] = (nl & 1u) ? fmaxf(ci*pl.x, di*ql.x) : 0.f;
  wv[1] = (nl & 2u) ? fmaxf(ci*pl.y, di*ql.y) : 0.f;
  wv[2] = (nl & 4u) ? fmaxf(ci*pl.z, di*ql.z) : 0.f;
  wv[3] = (nl & 8u) ? fmaxf(ci*pl.w, di*ql.w) : 0.f;
  wv[4] = (nh & 1u) ? fmaxf(ci*pH.x, di*qH.x) : 0.f;
  wv[5] = (nh & 2u) ? fmaxf(ci*pH.y, di*qH.y) : 0.f;
  wv[6] = (nh & 4u) ? fmaxf(ci*pH.z, di*qH.z) : 0.f;
  wv[7] = (nh & 8u) ? fmaxf(ci*pH.w, di*qH.w) : 0.f;
  #pragma unroll
  for (int t = 0; t < 4; ++t) {
    uint32_t lo = __float_as_uint(wv[2*t])   & 0xFFFF0000u;
    uint32_t hi = __float_as_uint(wv[2*t+1]) & 0xFFFF0000u;
    z += __uint_as_float(lo) + __uint_as_float(hi);
    A[t] = (lo >> 16) | hi;
  }
}

// ---- unified attention kernel: combo-major 1D grid (XCD-pinned B-tiles),
//      32 rows/wave, tiled-B coalesced loads, K-chunked partial accumulate ----
template<int CW, int NH, int KC>
__global__ __launch_bounds__(256, 4) void k_attn_t(
    const uint32_t* __restrict__ bm, const uint32_t* __restrict__ Wt,
    const float* __restrict__ ss, const float* __restrict__ p,
    const float* __restrict__ q, const float* __restrict__ m,
    float* __restrict__ part, float* __restrict__ Zp){
  int lane = threadIdx.x & 63;
  int wid  = threadIdx.x >> 6;
  // combo-major linearization: bid = x*(NH*KC) + h*KC + ch.
  // NH*KC % 8 == 0  =>  XCD (= bid % 8) is a function of (h,ch) only:
  // every row-block sharing this (h,ch)'s B-tiles runs on the SAME XCD's L2.
  constexpr int NB = NH * KC;
  int combo = blockIdx.x % NB;
  int x     = blockIdx.x / NB;
  int h  = combo / KC;
  int ch = combo % KC;
  int row0 = x * 128 + wid * 32;
  int g = lane >> 4, r = lane & 15;
  int ra = row0 + r, rb = ra + 16;
  int rac = ra < GN-1 ? ra : GN-1;
  int rbc = rb < GN-1 ? rb : GN-1;
  float mh = m[h];
  float sia = ss[(size_t)h*GN + rac];
  float sib = ss[(size_t)h*GN + rbc];
  float sma = sia + mh, smb = sib + mh;
  float Ma = sma > 0.f ? sma : 0.2f * sma;
  float Mb = smb > 0.f ? smb : 0.2f * smb;
  float cia = expf(sia - Ma), dia = expf(0.2f*sia - Ma);
  float cib = expf(sib - Mb), dib = expf(0.2f*sib - Mb);
  const float* ph = p + (size_t)h * PQS;
  const float* qh = q + (size_t)h * PQS;
  const uint32_t* bma = bm + (size_t)rac * WPR;
  const uint32_t* bmb = bm + (size_t)rbc * WPR;
  const uint32_t* wt = Wt + (size_t)h * NT * 1024;
  float4v accA[4], accB[4];
  #pragma unroll
  for (int n = 0; n < 4; ++n) { accA[n] = (float4v){0,0,0,0}; accB[n] = (float4v){0,0,0,0}; }
  float za = 0.f, zb = 0.f;
  const int w0 = ch * CW;
  for (int wb = 0; wb < CW/4; ++wb) {
    uint4 b4a = *(const uint4*)(bma + w0 + wb*4);
    uint4 b4b = *(const uint4*)(bmb + w0 + wb*4);
    uint32_t ba[4] = {b4a.x, b4a.y, b4a.z, b4a.w};
    uint32_t bb[4] = {b4b.x, b4b.y, b4b.z, b4b.w};
    #pragma unroll
    for (int e = 0; e < 4; ++e) {
      int w = w0 + wb*4 + e;
      int jb = w * 32;
      float4 pl = *(const float4*)(ph + jb + 4*g);
      float4 pH = *(const float4*)(ph + jb + 16 + 4*g);
      float4 ql = *(const float4*)(qh + jb + 4*g);
      float4 qH = *(const float4*)(qh + jb + 16 + 4*g);
      union { uint32_t u4[4]; short8v s; } Aa, Ab;
      build_A(ba[e], g, cia, dia, pl, pH, ql, qH, Aa.u4, za);
      build_A(bb[e], g, cib, dib, pl, pH, ql, qH, Ab.u4, zb);
      const uint32_t* tb = wt + (size_t)w * 1024 + r*16 + g*4;
      #pragma unroll
      for (int n = 0; n < 4; ++n) {
        union { uint32_t u4[4]; short8v s; } B;
        *(uint4*)B.u4 = *(const uint4*)(tb + n*256);
        accA[n] = __builtin_amdgcn_mfma_f32_16x16x32_bf16(Aa.s, B.s, accA[n], 0, 0, 0);
        accB[n] = __builtin_amdgcn_mfma_f32_16x16x32_bf16(Ab.s, B.s, accB[n], 0, 0, 0);
      }
    }
  }
  za += __shfl_xor(za, 16, 64); za += __shfl_xor(za, 32, 64);
  zb += __shfl_xor(zb, 16, 64); zb += __shfl_xor(zb, 32, 64);
  size_t pbase = ((size_t)ch * NH + h) * GN;
  #pragma unroll
  for (int reg = 0; reg < 4; ++reg) {
    int rwa = row0 + g*4 + reg;
    int rwb = rwa + 16;
    if (rwa < GN) {
      #pragma unroll
      for (int n = 0; n < 4; ++n) part[(pbase + rwa)*64 + n*16 + r] = accA[n][reg];
    }
    if (rwb < GN) {
      #pragma unroll
      for (int n = 0; n < 4; ++n) part[(pbase + rwb)*64 + n*16 + r] = accB[n][reg];
    }
  }
  if (lane < 16) {
    if (row0 + lane < GN)      Zp[pbase + row0 + lane]      = za;
    if (row0 + 16 + lane < GN) Zp[pbase + row0 + 16 + lane] = zb;
  }
}

// ---- combine L1 chunks: normalize, ELU, bf16 h1 ----
__global__ void k_reduce1(const float* __restrict__ part1, const float* __restrict__ Zp1,
                          uint16_t* __restrict__ h1bf){
  int idx = blockIdx.x * 256 + threadIdx.x;
  if (idx >= GNH*GN*64) return;
  int o = idx & 63;
  int t = idx >> 6;
  int n = t % GN;
  int h = t / GN;
  float s = 0.f, z = 0.f;
  #pragma unroll
  for (int c = 0; c < KC1; ++c) {
    s += part1[(((size_t)c*GNH + h)*GN + n)*64 + o];
    z += Zp1[((size_t)c*GNH + h)*GN + n];
  }
  float v = s / z;
  v = v > 0.f ? v : (expf(v) - 1.f);
  h1bf[(size_t)n * GFIN + h*64 + o] = f2bf(v);
}

// ---- layer-2 GEMM: 4 rows/wave; tiled Whc2 + scores ----
__global__ __launch_bounds__(256) void k_gemm2(
    const uint16_t* __restrict__ h1bf, const float* __restrict__ W2f,
    const float* __restrict__ as2f, const float* __restrict__ at2f,
    uint32_t* __restrict__ Wt2, float* __restrict__ ss2, float* __restrict__ st2){
  int lane = threadIdx.x & 63;
  int wid  = threadIdx.x >> 6;
  int row0 = blockIdx.x * 16 + wid * 4;
  const uint32_t* xr[4];
  #pragma unroll
  for (int r = 0; r < 4; ++r) {
    int rc = row0 + r; if (rc > GN-1) rc = GN-1;
    xr[r] = (const uint32_t*)(h1bf + (size_t)rc * GFIN);
  }
  const float* W = W2f + lane;
  float acc[4];
  #pragma unroll
  for (int r = 0; r < 4; ++r) acc[r] = 0.f;
  #pragma unroll 4
  for (int fp = 0; fp < GFIN/2; ++fp) {
    float W0 = W[(2*fp)*64];
    float W1v = W[(2*fp+1)*64];
    #pragma unroll
    for (int r = 0; r < 4; ++r) {
      uint32_t u = xr[r][fp];
      acc[r] = fmaf(__uint_as_float(u << 16),         W0,  acc[r]);
      acc[r] = fmaf(__uint_as_float(u & 0xFFFF0000u), W1v, acc[r]);
    }
  }
  uint32_t pk0 = (uint32_t)f2bf(acc[0]) | ((uint32_t)f2bf(acc[1]) << 16);
  uint32_t pk1 = (uint32_t)f2bf(acc[2]) | ((uint32_t)f2bf(acc[3]) << 16);
  int tw = row0 >> 5;
  int mm = (row0 >> 2) & 7;
  int d0 = ((mm & 3) << 2) | ((mm >> 2) << 1);     // 0,4,8,12,2,6,10,14
  *(uint2*)(Wt2 + (size_t)tw*1024 + lane*16 + d0) = make_uint2(pk0, pk1);
  float av = as2f[lane], tv = at2f[lane];
  #pragma unroll
  for (int r = 0; r < 4; ++r) {
    int row = row0 + r;
    if (row >= GN) break;
    float rs = av * acc[r];
    float rt = tv * acc[r];
    #pragma unroll
    for (int d = 32; d; d >>= 1) { rs += __shfl_xor(rs, d, 64); rt += __shfl_xor(rt, d, 64); }
    if (lane == 0) { ss2[row] = rs; st2[row] = rt; }
  }
}

// ---- combine L2 chunks: normalize, f32 logits ----
__global__ void k_reduce2(const float* __restrict__ part2, const float* __restrict__ Zp2,
                          float* __restrict__ out){
  int idx = blockIdx.x * 256 + threadIdx.x;
  if (idx >= GN * GNC) return;
  int n = idx / GNC, c = idx - n * GNC;
  float s = 0.f, z = 0.f;
  #pragma unroll 8
  for (int ch = 0; ch < KC2; ++ch) {
    s += part2[((size_t)ch * GN + n) * 64 + c];
    z += Zp2[(size_t)ch * GN + n];
  }
  out[idx] = s / z;
}

// ---- adjacency echo (f32), written LAST over partial scratch ----
__global__ void k_echo(const uint32_t* __restrict__ bm, float* __restrict__ echo){
  int idx = blockIdx.x * 256 + threadIdx.x;
  if (idx >= GN * WPR) return;
  int row = idx / WPR, w = idx - row * WPR;
  int j0 = w * 32;
  if (j0 >= GN) return;
  uint32_t bits = bm[idx];
  float* dst = echo + (size_t)row * GN + j0;
  int lim = GN - j0;
  if (lim >= 32) {
    float4* d4 = (float4*)dst;
    #pragma unroll
    for (int g = 0; g < 8; ++g) {
      float4 f;
      f.x = ((bits >> (4*g+0)) & 1u) ? 1.f : 0.f;
      f.y = ((bits >> (4*g+1)) & 1u) ? 1.f : 0.f;
      f.z = ((bits >> (4*g+2)) & 1u) ? 1.f : 0.f;
      f.w = ((bits >> (4*g+3)) & 1u) ? 1.f : 0.f;
      d4[g] = f;
    }
  } else {
    for (int b = 0; b < lim; ++b) dst[b] = ((bits >> b) & 1u) ? 1.f : 0.f;
  }
}

extern "C" void kernel_launch(void* const* d_in, const int* in_sizes, int n_in,
                              void* d_out, int out_size, void* d_ws, size_t ws_size,
                              hipStream_t stream){
  const float* x   = (const float*)d_in[0];
  const int*   adj = (const int*)d_in[1];
  const float* W1  = (const float*)d_in[2];
  const float* as1 = (const float*)d_in[3];
  const float* at1 = (const float*)d_in[4];
  const float* W2  = (const float*)d_in[5];
  const float* as2 = (const float*)d_in[6];
  const float* at2 = (const float*)d_in[7];
  float* out  = (float*)d_out;                    // f32 logits [6000,40]
  float* echo = out + (size_t)GN * GNC;           // f32 adj echo [6000,6000]
  (void)in_sizes; (void)n_in; (void)out_size; (void)ws_size;

  // chunk partials live in echo region until k_echo overwrites it (last)
  float* part1 = echo;                                  // 4*8*6000*64 = 12.29M f32
  float* Zp1   = part1 + (size_t)KC1 * GNH * GN * 64;   // 192K f32
  float* part2 = Zp1   + (size_t)KC1 * GNH * GN;        // 24*6000*64 = 9.22M f32
  float* Zp2   = part2 + (size_t)KC2 * GN * 64;         // 144K f32

  char* wsb = (char*)d_ws;
  size_t off = 0;
  auto alloc = [&](size_t bytes) -> void* {
    void* r = wsb + off;
    off = (off + bytes + 255) & ~(size_t)255;
    return r;
  };
  uint32_t* bm   = (uint32_t*)alloc((size_t)GN * WPR * 4);
  float*    W2f  = (float*)alloc((size_t)GFIN * 64 * 4);
  float*    as2f = (float*)alloc(64 * 4);
  float*    at2f = (float*)alloc(64 * 4);
  uint32_t* Wt1  = (uint32_t*)alloc((size_t)GNH * NT * 1024 * 4);  // tiled bf16 Wh1
  uint32_t* Wt2  = (uint32_t*)alloc((size_t)NT * 1024 * 4);        // tiled bf16 Wh2
  float*    ss1  = (float*)alloc((size_t)GNH * GN * 4);
  float*    st1  = (float*)alloc((size_t)GNH * GN * 4);
  float*    p1   = (float*)alloc((size_t)GNH * PQS * 4);
  float*    q1   = (float*)alloc((size_t)GNH * PQS * 4);
  float*    m1   = (float*)alloc(64);
  uint16_t* h1bf = (uint16_t*)alloc((size_t)GN * GFIN * 2);
  float*    ss2  = (float*)alloc((size_t)GN * 4);
  float*    st2  = (float*)alloc((size_t)GN * 4);
  float*    p2   = (float*)alloc((size_t)PQS * 4);
  float*    q2   = (float*)alloc((size_t)PQS * 4);
  float*    m2   = (float*)alloc(64);

  const int NX = (GN + 127) / 128;    // 47 row-blocks

  hipLaunchKernelGGL(k_prep, dim3(192), dim3(256), 0, stream,
      W2, as2, at2, W2f, as2f, at2f, Wt1, Wt2, p1, q1, p2, q2);
  hipLaunchKernelGGL(k_bitmask, dim3(GN*WPR/256), dim3(256), 0, stream, adj, bm);
  hipLaunchKernelGGL(k_gemm1, dim3((GN+31)/32, GNH), dim3(256), 0, stream,
      x, W1, as1, at1, Wt1, ss1, st1);
  hipLaunchKernelGGL(k_stats, dim3(GNH), dim3(256), 0, stream, st1, p1, q1, m1);
  hipLaunchKernelGGL((k_attn_t<CW1, GNH, KC1>), dim3(NX * GNH * KC1), dim3(256), 0, stream,
      bm, Wt1, ss1, p1, q1, m1, part1, Zp1);
  hipLaunchKernelGGL(k_reduce1, dim3(GNH*GN*64/256), dim3(256), 0, stream,
      part1, Zp1, h1bf);
  hipLaunchKernelGGL(k_gemm2, dim3((GN+15)/16), dim3(256), 0, stream,
      h1bf, W2f, as2f, at2f, Wt2, ss2, st2);
  hipLaunchKernelGGL(k_stats, dim3(1), dim3(256), 0, stream, st2, p2, q2, m2);
  hipLaunchKernelGGL((k_attn_t<CW2, 1, KC2>), dim3(NX * KC2), dim3(256), 0, stream,
      bm, Wt2, ss2, p2, q2, m2, part2, Zp2);
  hipLaunchKernelGGL(k_reduce2, dim3((GN*GNC+255)/256), dim3(256), 0, stream,
      part2, Zp2, out);
  hipLaunchKernelGGL(k_echo, dim3(GN*WPR/256), dim3(256), 0, stream, bm, echo);
}

// Round 9
// 365.979 us; speedup vs baseline: 10.7118x; 1.7016x over previous
//
#include <hip/hip_runtime.h>
#include <hip/hip_bf16.h>
#include <stdint.h>

#define GN   6000
#define GFIN 512
#define GNH  8
#define GNC  40
#define WPR  192           // bitmask words per row (192*32 = 6144)
#define NT   192           // j-tiles per head (tile 187 part-pad, 188..191 zero)
#define NRT  375           // row-tiles (16 rows each), 375*16 = 6000 exact
#define PQS  6144          // per-head stride of p/q (zero-padded tail)
#define KC1  4             // attn1 K-chunks (48 w each)
#define CW1  48
#define KC2  24            // attn2 K-chunks (8 w each)
#define CW2  8

typedef __attribute__((ext_vector_type(8))) short short8v;   // 8 bf16
typedef __attribute__((ext_vector_type(4))) float float4v;   // MFMA acc

__device__ __forceinline__ uint16_t f2bf(float f){
  uint32_t u = __float_as_uint(f);
  return (uint16_t)((u + 0x7FFFu + ((u >> 16) & 1u)) >> 16);
}
__device__ __forceinline__ uint32_t packbf(float a, float b){
  return (uint32_t)f2bf(a) | ((uint32_t)f2bf(b) << 16);
}
// k-pair base for fragment dword t within k-group g (16x16x32 bf16 layout)
__device__ __forceinline__ int kmap(int g, int t){
  return (t < 2) ? 4*g + 2*t : 16 + 4*g + 2*(t - 2);
}

// ---- prep: pad a2; zero p/q; zero Wt pad tiles (187..191) ----
__global__ void k_prep(const float* __restrict__ as2, const float* __restrict__ at2,
                       float* __restrict__ as2f, float* __restrict__ at2f,
                       uint32_t* __restrict__ Wt1, uint32_t* __restrict__ Wt2,
                       float* __restrict__ p1, float* __restrict__ q1,
                       float* __restrict__ p2, float* __restrict__ q2){
  int i = blockIdx.x * 256 + threadIdx.x;
  if (i < 64) { as2f[i] = (i < GNC) ? as2[i] : 0.f; at2f[i] = (i < GNC) ? at2[i] : 0.f; }
  if (i < GNH*PQS) { p1[i] = 0.f; q1[i] = 0.f; }
  if (i < PQS) { p2[i] = 0.f; q2[i] = 0.f; }
  if (i < GNH*5*1024) {                      // Wt1 tiles 187..191 per head
    int h = i / 5120, rem = i - h * 5120;
    Wt1[((size_t)h*NT + 187)*1024 + rem] = 0u;
  }
  if (i < 5*1024) Wt2[(size_t)187*1024 + i] = 0u;
}

// ---- adjacency -> bitmask ----
__global__ void k_bitmask(const int* __restrict__ adj, uint32_t* __restrict__ bm){
  int idx = blockIdx.x * 256 + threadIdx.x;
  if (idx >= GN * WPR) return;
  int row = idx / WPR, w = idx - row * WPR;
  int j0 = w * 32;
  uint32_t bits = 0u;
  if (j0 < GN) {
    const int* a = adj + (size_t)row * GN + j0;
    int lim = GN - j0;
    if (lim >= 32) {
      const int4* a4 = (const int4*)a;
      #pragma unroll
      for (int g = 0; g < 8; ++g) {
        int4 v = a4[g];
        bits |= (v.x != 0 ? 1u : 0u) << (4*g);
        bits |= (v.y != 0 ? 1u : 0u) << (4*g + 1);
        bits |= (v.z != 0 ? 1u : 0u) << (4*g + 2);
        bits |= (v.w != 0 ? 1u : 0u) << (4*g + 3);
      }
    } else {
      for (int b = 0; b < lim; ++b) bits |= (a[b] != 0 ? 1u : 0u) << b;
    }
  }
  bm[idx] = bits;
}

// ---- x (f32 [6000][512]) -> A-tiled bf16: xt[(rt*16+kt)*256 + lane*4 + e] ----
__global__ void k_xtile(const float* __restrict__ x, uint32_t* __restrict__ xt){
  int idx = blockIdx.x * 256 + threadIdx.x;      // 375*16*256 = 1,536,000 exact
  int e = idx & 3, lane = (idx >> 2) & 63, kt = (idx >> 8) & 15, rt = idx >> 12;
  int g = lane >> 4, r = lane & 15;
  int k0 = kt*32 + kmap(g, e);
  const float* xp = x + (size_t)(rt*16 + r) * GFIN + k0;
  xt[idx] = packbf(xp[0], xp[1]);
}

// ---- W1 (f32 [8][512][64]) -> B-tiled bf16 ----
__global__ void k_wtile1(const float* __restrict__ W1, uint32_t* __restrict__ Wb1){
  int idx = blockIdx.x * 256 + threadIdx.x;      // 8*16*1024 = 131072 exact
  int e = idx & 3, lane = (idx >> 2) & 63, n = (idx >> 8) & 3, kt = (idx >> 10) & 15, h = idx >> 14;
  int g = lane >> 4, col = n*16 + (lane & 15);
  int k0 = kt*32 + kmap(g, e);
  const float* wp = W1 + ((size_t)h*GFIN + k0) * 64 + col;
  Wb1[idx] = packbf(wp[0], wp[64]);
}

// ---- W2 (f32 [512][40]) -> B-tiled bf16, cols padded to 64 ----
__global__ void k_wtile2(const float* __restrict__ W2, uint32_t* __restrict__ Wb2){
  int idx = blockIdx.x * 256 + threadIdx.x;      // 16*1024 = 16384 exact
  int e = idx & 3, lane = (idx >> 2) & 63, n = (idx >> 8) & 3, kt = idx >> 10;
  int g = lane >> 4, col = n*16 + (lane & 15);
  int k0 = kt*32 + kmap(g, e);
  float v0 = (col < GNC) ? W2[(size_t)k0*GNC + col]     : 0.f;
  float v1 = (col < GNC) ? W2[(size_t)(k0+1)*GNC + col] : 0.f;
  Wb2[idx] = packbf(v0, v1);
}

// ---- MFMA GEMM: At[rt][kt] (16x32) x Bt[h][kt] (32x64) -> Wh tiled bf16 + scores ----
__global__ __launch_bounds__(256) void k_gemm_mfma(
    const uint32_t* __restrict__ At, const uint32_t* __restrict__ Bt,
    const float* __restrict__ asv, const float* __restrict__ atv,
    uint32_t* __restrict__ Wt, float* __restrict__ ss, float* __restrict__ st){
  int lane = threadIdx.x & 63;
  int wid  = threadIdx.x >> 6;
  int h  = blockIdx.y;
  int rt = blockIdx.x * 4 + wid;
  if (rt >= NRT) return;
  int g = lane >> 4, r = lane & 15;
  const uint32_t* Ab = At + (size_t)rt * 16 * 256 + lane * 4;
  const uint32_t* Bb = Bt + (size_t)h * 16 * 1024 + lane * 4;
  float4v acc[4];
  #pragma unroll
  for (int n = 0; n < 4; ++n) acc[n] = (float4v){0,0,0,0};
  for (int kt = 0; kt < 16; ++kt) {
    union { uint32_t u4[4]; short8v s; } A;
    *(uint4*)A.u4 = *(const uint4*)(Ab + kt*256);
    #pragma unroll
    for (int n = 0; n < 4; ++n) {
      union { uint32_t u4[4]; short8v s; } B;
      *(uint4*)B.u4 = *(const uint4*)(Bb + kt*1024 + n*256);
      acc[n] = __builtin_amdgcn_mfma_f32_16x16x32_bf16(A.s, B.s, acc[n], 0, 0, 0);
    }
  }
  // Wh store: rows row0+4g+{reg}, col n*16+r -> lane-major tile dwords
  int row0 = rt * 16;
  int t01  = (row0 & 16) ? 2 : 0;
  uint32_t* dst = Wt + ((size_t)h*NT + (row0 >> 5)) * 1024 + lane*4 + t01;
  #pragma unroll
  for (int n = 0; n < 4; ++n)
    *(uint2*)(dst + n*256) = make_uint2(packbf(acc[n][0], acc[n][1]),
                                        packbf(acc[n][2], acc[n][3]));
  // scores: rs/rt over 64 cols (reduce across r lanes within each g group)
  float av[4], tv[4];
  #pragma unroll
  for (int n = 0; n < 4; ++n) { av[n] = asv[h*64 + n*16 + r]; tv[n] = atv[h*64 + n*16 + r]; }
  float pr[4], pt[4];
  #pragma unroll
  for (int reg = 0; reg < 4; ++reg) {
    float a = 0.f, b = 0.f;
    #pragma unroll
    for (int n = 0; n < 4; ++n) { a = fmaf(av[n], acc[n][reg], a); b = fmaf(tv[n], acc[n][reg], b); }
    #pragma unroll
    for (int d = 1; d < 16; d <<= 1) { a += __shfl_xor(a, d, 64); b += __shfl_xor(b, d, 64); }
    pr[reg] = a; pt[reg] = b;
  }
  if (r < 4) {
    ss[(size_t)h*GN + row0 + 4*g + r] = pr[r];
    st[(size_t)h*GN + row0 + 4*g + r] = pt[r];
  }
}

// ---- column stats: p=exp(s), q=exp(0.2 s) (stride PQS), m=max(s) ----
__global__ void k_stats(const float* __restrict__ s_tgt, float* __restrict__ p,
                        float* __restrict__ q, float* __restrict__ m){
  int h = blockIdx.x;
  __shared__ float red[256];
  float mx = -3.0e38f;
  for (int n = threadIdx.x; n < GN; n += 256) {
    float s = s_tgt[(size_t)h*GN + n];
    p[(size_t)h*PQS + n] = expf(s);
    q[(size_t)h*PQS + n] = expf(0.2f * s);
    mx = fmaxf(mx, s);
  }
  red[threadIdx.x] = mx;
  __syncthreads();
  for (int d = 128; d > 0; d >>= 1) {
    if (threadIdx.x < d) red[threadIdx.x] = fmaxf(red[threadIdx.x], red[threadIdx.x + d]);
    __syncthreads();
  }
  if (threadIdx.x == 0) m[h] = red[0];
}

__device__ __forceinline__ void build_A(uint32_t bw, int g, float ci, float di,
    const float4& pl, const float4& pH, const float4& ql, const float4& qH,
    uint32_t A[4], float& z){
  uint32_t nl = (bw >> (4*g)) & 0xFu;
  uint32_t nh = (bw >> (16 + 4*g)) & 0xFu;
  float wv[8];
  wv[0] = (nl & 1u) ? fmaxf(ci*pl.x, di*ql.x) : 0.f;
  wv[1] = (nl & 2u) ? fmaxf(ci*pl.y, di*ql.y) : 0.f;
  wv[2] = (nl & 4u) ? fmaxf(ci*pl.z, di*ql.z) : 0.f;
  wv[3] = (nl & 8u) ? fmaxf(ci*pl.w, di*ql.w) : 0.f;
  wv[4] = (nh & 1u) ? fmaxf(ci*pH.x, di*qH.x) : 0.f;
  wv[5] = (nh & 2u) ? fmaxf(ci*pH.y, di*qH.y) : 0.f;
  wv[6] = (nh & 4u) ? fmaxf(ci*pH.z, di*qH.z) : 0.f;
  wv[7] = (nh & 8u) ? fmaxf(ci*pH.w, di*qH.w) : 0.f;
  #pragma unroll
  for (int t = 0; t < 4; ++t) {
    uint32_t lo = __float_as_uint(wv[2*t])   & 0xFFFF0000u;
    uint32_t hi = __float_as_uint(wv[2*t+1]) & 0xFFFF0000u;
    z += __uint_as_float(lo) + __uint_as_float(hi);
    A[t] = (lo >> 16) | hi;
  }
}

// ---- attention: combo-major grid (XCD-pinned B-tiles), 32 rows/wave ----
template<int CW, int NH, int KC>
__global__ __launch_bounds__(256, 4) void k_attn_t(
    const uint32_t* __restrict__ bm, const uint32_t* __restrict__ Wt,
    const float* __restrict__ ss, const float* __restrict__ p,
    const float* __restrict__ q, const float* __restrict__ m,
    float* __restrict__ part, float* __restrict__ Zp){
  int lane = threadIdx.x & 63;
  int wid  = threadIdx.x >> 6;
  constexpr int NB = NH * KC;        // NB % 8 == 0 -> (h,ch) pinned to one XCD
  int combo = blockIdx.x % NB;
  int x     = blockIdx.x / NB;
  int h  = combo / KC;
  int ch = combo % KC;
  int row0 = x * 128 + wid * 32;
  int g = lane >> 4, r = lane & 15;
  int ra = row0 + r, rb = ra + 16;
  int rac = ra < GN-1 ? ra : GN-1;
  int rbc = rb < GN-1 ? rb : GN-1;
  float mh = m[h];
  float sia = ss[(size_t)h*GN + rac];
  float sib = ss[(size_t)h*GN + rbc];
  float sma = sia + mh, smb = sib + mh;
  float Ma = sma > 0.f ? sma : 0.2f * sma;
  float Mb = smb > 0.f ? smb : 0.2f * smb;
  float cia = expf(sia - Ma), dia = expf(0.2f*sia - Ma);
  float cib = expf(sib - Mb), dib = expf(0.2f*sib - Mb);
  const float* ph = p + (size_t)h * PQS;
  const float* qh = q + (size_t)h * PQS;
  const uint32_t* bma = bm + (size_t)rac * WPR;
  const uint32_t* bmb = bm + (size_t)rbc * WPR;
  const uint32_t* wt = Wt + (size_t)h * NT * 1024;
  float4v accA[4], accB[4];
  #pragma unroll
  for (int n = 0; n < 4; ++n) { accA[n] = (float4v){0,0,0,0}; accB[n] = (float4v){0,0,0,0}; }
  float za = 0.f, zb = 0.f;
  const int w0 = ch * CW;
  for (int wb = 0; wb < CW/4; ++wb) {
    uint4 b4a = *(const uint4*)(bma + w0 + wb*4);
    uint4 b4b = *(const uint4*)(bmb + w0 + wb*4);
    uint32_t ba[4] = {b4a.x, b4a.y, b4a.z, b4a.w};
    uint32_t bb[4] = {b4b.x, b4b.y, b4b.z, b4b.w};
    #pragma unroll
    for (int e = 0; e < 4; ++e) {
      int w = w0 + wb*4 + e;
      int jb = w * 32;
      float4 pl = *(const float4*)(ph + jb + 4*g);
      float4 pH = *(const float4*)(ph + jb + 16 + 4*g);
      float4 ql = *(const float4*)(qh + jb + 4*g);
      float4 qH = *(const float4*)(qh + jb + 16 + 4*g);
      union { uint32_t u4[4]; short8v s; } Aa, Ab;
      build_A(ba[e], g, cia, dia, pl, pH, ql, qH, Aa.u4, za);
      build_A(bb[e], g, cib, dib, pl, pH, ql, qH, Ab.u4, zb);
      const uint32_t* tb = wt + (size_t)w * 1024 + lane * 4;
      #pragma unroll
      for (int n = 0; n < 4; ++n) {
        union { uint32_t u4[4]; short8v s; } B;
        *(uint4*)B.u4 = *(const uint4*)(tb + n*256);
        accA[n] = __builtin_amdgcn_mfma_f32_16x16x32_bf16(Aa.s, B.s, accA[n], 0, 0, 0);
        accB[n] = __builtin_amdgcn_mfma_f32_16x16x32_bf16(Ab.s, B.s, accB[n], 0, 0, 0);
      }
    }
  }
  za += __shfl_xor(za, 16, 64); za += __shfl_xor(za, 32, 64);
  zb += __shfl_xor(zb, 16, 64); zb += __shfl_xor(zb, 32, 64);
  size_t pbase = ((size_t)ch * NH + h) * GN;
  #pragma unroll
  for (int reg = 0; reg < 4; ++reg) {
    int rwa = row0 + g*4 + reg;
    int rwb = rwa + 16;
    if (rwa < GN) {
      #pragma unroll
      for (int n = 0; n < 4; ++n) part[(pbase + rwa)*64 + n*16 + r] = accA[n][reg];
    }
    if (rwb < GN) {
      #pragma unroll
      for (int n = 0; n < 4; ++n) part[(pbase + rwb)*64 + n*16 + r] = accB[n][reg];
    }
  }
  if (lane < 16) {
    if (row0 + lane < GN)      Zp[pbase + row0 + lane]      = za;
    if (row0 + 16 + lane < GN) Zp[pbase + row0 + 16 + lane] = zb;
  }
}

// ---- combine L1 chunks: normalize, ELU, write h1 in A-tile bf16 layout ----
__global__ void k_reduce1(const float* __restrict__ part1, const float* __restrict__ Zp1,
                          uint32_t* __restrict__ h1t){
  int idx = blockIdx.x * 256 + threadIdx.x;
  if (idx >= GNH*GN*64) return;
  int o = idx & 63;
  int t = idx >> 6;
  int n = t % GN;
  int h = t / GN;
  float s = 0.f, z = 0.f;
  #pragma unroll
  for (int c = 0; c < KC1; ++c) {
    s += part1[(((size_t)c*GNH + h)*GN + n)*64 + o];
    z += Zp1[((size_t)c*GNH + h)*GN + n];
  }
  float v = s / z;
  v = v > 0.f ? v : (expf(v) - 1.f);
  // A-tile position: row=n, k=h*64+o
  int rt = n >> 4, r = n & 15;
  int k = h*64 + o;
  int kt = k >> 5, joff = k & 31;
  int g, tt, b;
  if (joff < 16) { g = joff >> 2; tt = (joff & 3) >> 1;       b = joff & 1; }
  else { int jo = joff - 16; g = jo >> 2; tt = 2 + ((jo & 3) >> 1); b = jo & 1; }
  size_t dw = ((size_t)(rt*16 + kt))*256 + (g*16 + r)*4 + tt;
  ((uint16_t*)h1t)[dw*2 + b] = f2bf(v);
}

// ---- combine L2 chunks: normalize, f32 logits ----
__global__ void k_reduce2(const float* __restrict__ part2, const float* __restrict__ Zp2,
                          float* __restrict__ out){
  int idx = blockIdx.x * 256 + threadIdx.x;
  if (idx >= GN * GNC) return;
  int n = idx / GNC, c = idx - n * GNC;
  float s = 0.f, z = 0.f;
  #pragma unroll 8
  for (int ch = 0; ch < KC2; ++ch) {
    s += part2[((size_t)ch * GN + n) * 64 + c];
    z += Zp2[(size_t)ch * GN + n];
  }
  out[idx] = s / z;
}

// ---- adjacency echo (f32), written LAST over all scratch ----
__global__ void k_echo(const uint32_t* __restrict__ bm, float* __restrict__ echo){
  int idx = blockIdx.x * 256 + threadIdx.x;
  if (idx >= GN * WPR) return;
  int row = idx / WPR, w = idx - row * WPR;
  int j0 = w * 32;
  if (j0 >= GN) return;
  uint32_t bits = bm[idx];
  float* dst = echo + (size_t)row * GN + j0;
  int lim = GN - j0;
  if (lim >= 32) {
    float4* d4 = (float4*)dst;
    #pragma unroll
    for (int g = 0; g < 8; ++g) {
      float4 f;
      f.x = ((bits >> (4*g+0)) & 1u) ? 1.f : 0.f;
      f.y = ((bits >> (4*g+1)) & 1u) ? 1.f : 0.f;
      f.z = ((bits >> (4*g+2)) & 1u) ? 1.f : 0.f;
      f.w = ((bits >> (4*g+3)) & 1u) ? 1.f : 0.f;
      d4[g] = f;
    }
  } else {
    for (int b = 0; b < lim; ++b) dst[b] = ((bits >> b) & 1u) ? 1.f : 0.f;
  }
}

extern "C" void kernel_launch(void* const* d_in, const int* in_sizes, int n_in,
                              void* d_out, int out_size, void* d_ws, size_t ws_size,
                              hipStream_t stream){
  const float* x   = (const float*)d_in[0];
  const int*   adj = (const int*)d_in[1];
  const float* W1  = (const float*)d_in[2];
  const float* as1 = (const float*)d_in[3];
  const float* at1 = (const float*)d_in[4];
  const float* W2  = (const float*)d_in[5];
  const float* as2 = (const float*)d_in[6];
  const float* at2 = (const float*)d_in[7];
  float* out  = (float*)d_out;                    // f32 logits [6000,40]
  float* echo = out + (size_t)GN * GNC;           // f32 adj echo [6000,6000]
  (void)in_sizes; (void)n_in; (void)out_size; (void)ws_size;

  // scratch in echo region (all dead before k_echo overwrites; no overlaps)
  float*    part1 = echo;                                   // 12.288M f32
  float*    Zp1   = part1 + (size_t)KC1 * GNH * GN * 64;    // 192K
  float*    part2 = Zp1   + (size_t)KC1 * GNH * GN;         // 9.216M
  float*    Zp2   = part2 + (size_t)KC2 * GN * 64;          // 144K
  uint32_t* h1t   = (uint32_t*)(Zp2 + (size_t)KC2 * GN);    // 1.536M dw
  uint32_t* xt    = h1t + (size_t)NRT * 16 * 256;           // 1.536M dw
  // total ~100 MB <= 144 MB

  char* wsb = (char*)d_ws;
  size_t off = 0;
  auto alloc = [&](size_t bytes) -> void* {
    void* r = wsb + off;
    off = (off + bytes + 255) & ~(size_t)255;
    return r;
  };
  uint32_t* bm   = (uint32_t*)alloc((size_t)GN * WPR * 4);
  uint32_t* Wt1  = (uint32_t*)alloc((size_t)GNH * NT * 1024 * 4);
  uint32_t* Wt2  = (uint32_t*)alloc((size_t)NT * 1024 * 4);
  uint32_t* Wb1  = (uint32_t*)alloc((size_t)GNH * 16 * 1024 * 4);
  uint32_t* Wb2  = (uint32_t*)alloc((size_t)16 * 1024 * 4);
  float*    as2f = (float*)alloc(64 * 4);
  float*    at2f = (float*)alloc(64 * 4);
  float*    ss1  = (float*)alloc((size_t)GNH * GN * 4);
  float*    st1  = (float*)alloc((size_t)GNH * GN * 4);
  float*    p1   = (float*)alloc((size_t)GNH * PQS * 4);
  float*    q1   = (float*)alloc((size_t)GNH * PQS * 4);
  float*    m1   = (float*)alloc(64);
  float*    ss2  = (float*)alloc((size_t)GN * 4);
  float*    st2  = (float*)alloc((size_t)GN * 4);
  float*    p2   = (float*)alloc((size_t)PQS * 4);
  float*    q2   = (float*)alloc((size_t)PQS * 4);
  float*    m2   = (float*)alloc(64);
  // ~13 MB ws

  const int NX = (GN + 127) / 128;    // 47 row-blocks (attn)

  hipLaunchKernelGGL(k_prep, dim3(192), dim3(256), 0, stream,
      as2, at2, as2f, at2f, Wt1, Wt2, p1, q1, p2, q2);
  hipLaunchKernelGGL(k_bitmask, dim3(GN*WPR/256), dim3(256), 0, stream, adj, bm);
  hipLaunchKernelGGL(k_xtile, dim3(NRT*16*256/256), dim3(256), 0, stream, x, xt);
  hipLaunchKernelGGL(k_wtile1, dim3(512), dim3(256), 0, stream, W1, Wb1);
  hipLaunchKernelGGL(k_wtile2, dim3(64), dim3(256), 0, stream, W2, Wb2);
  hipLaunchKernelGGL(k_gemm_mfma, dim3((NRT+3)/4, GNH), dim3(256), 0, stream,
      xt, Wb1, as1, at1, Wt1, ss1, st1);
  hipLaunchKernelGGL(k_stats, dim3(GNH), dim3(256), 0, stream, st1, p1, q1, m1);
  hipLaunchKernelGGL((k_attn_t<CW1, GNH, KC1>), dim3(NX * GNH * KC1), dim3(256), 0, stream,
      bm, Wt1, ss1, p1, q1, m1, part1, Zp1);
  hipLaunchKernelGGL(k_reduce1, dim3(GNH*GN*64/256), dim3(256), 0, stream,
      part1, Zp1, h1t);
  hipLaunchKernelGGL(k_gemm_mfma, dim3((NRT+3)/4, 1), dim3(256), 0, stream,
      h1t, Wb2, as2f, at2f, Wt2, ss2, st2);
  hipLaunchKernelGGL(k_stats, dim3(1), dim3(256), 0, stream, st2, p2, q2, m2);
  hipLaunchKernelGGL((k_attn_t<CW2, 1, KC2>), dim3(NX * KC2), dim3(256), 0, stream,
      bm, Wt2, ss2, p2, q2, m2, part2, Zp2);
  hipLaunchKernelGGL(k_reduce2, dim3((GN*GNC+255)/256), dim3(256), 0, stream,
      part2, Zp2, out);
  hipLaunchKernelGGL(k_echo, dim3(GN*WPR/256), dim3(256), 0, stream, bm, echo);
}

// Round 10
// 278.461 us; speedup vs baseline: 14.0784x; 1.3143x over previous
//
#include <hip/hip_runtime.h>
#include <hip/hip_bf16.h>
#include <stdint.h>

#define GN   6000
#define GNP2 3000          // row pairs
#define GFIN 512
#define GNH  8
#define GNC  40
#define WPR  192           // bitmask words per row (192*32 = 6144)
#define NT   192           // j-tiles per head (tile 187 part-pad, 188..191 zero)
#define NRT  375           // row-tiles (16 rows), 375*16 = 6000 exact
#define PQS  6144
#define KC1  8             // attn1 K-chunks (24 w each)
#define CW1  24
#define KC2  24            // attn2 K-chunks (8 w each)
#define CW2  8

typedef __attribute__((ext_vector_type(8))) short short8v;   // 8 bf16
typedef __attribute__((ext_vector_type(4))) float float4v;   // MFMA acc

__device__ __forceinline__ uint16_t f2bf(float f){
  uint32_t u = __float_as_uint(f);
  return (uint16_t)((u + 0x7FFFu + ((u >> 16) & 1u)) >> 16);
}
__device__ __forceinline__ float bf2f(uint16_t b){
  union { uint32_t u; float f; } v; v.u = ((uint32_t)b) << 16; return v.f;
}
__device__ __forceinline__ uint32_t packbf(float a, float b){
  return (uint32_t)f2bf(a) | ((uint32_t)f2bf(b) << 16);
}
__device__ __forceinline__ uint32_t cvtpk(float lo, float hi){
  uint32_t r;
  asm("v_cvt_pk_bf16_f32 %0, %1, %2" : "=v"(r) : "v"(lo), "v"(hi));
  return r;
}
// k-pair base for fragment dword t within k-group g (16x16x32 bf16 layout)
__device__ __forceinline__ int kmap(int g, int t){
  return (t < 2) ? 4*g + 2*t : 16 + 4*g + 2*(t - 2);
}

// ---- prep: pad a2; zero p/q tails; zero Wt pad tiles (187..191) ----
__global__ void k_prep(const float* __restrict__ as2, const float* __restrict__ at2,
                       float* __restrict__ as2f, float* __restrict__ at2f,
                       uint32_t* __restrict__ Wt1, uint32_t* __restrict__ Wt2,
                       float* __restrict__ p1, float* __restrict__ q1,
                       float* __restrict__ p2, float* __restrict__ q2){
  int i = blockIdx.x * 256 + threadIdx.x;
  if (i < 64) { as2f[i] = (i < GNC) ? as2[i] : 0.f; at2f[i] = (i < GNC) ? at2[i] : 0.f; }
  if (i < GNH*PQS) { p1[i] = 0.f; q1[i] = 0.f; }
  if (i < PQS) { p2[i] = 0.f; q2[i] = 0.f; }
  if (i < GNH*5*1024) {
    int h = i / 5120, rem = i - h * 5120;
    Wt1[((size_t)h*NT + 187)*1024 + rem] = 0u;
  }
  if (i < 5*1024) Wt2[(size_t)187*1024 + i] = 0u;
}

// ---- adjacency -> bitmask ----
__global__ void k_bitmask(const int* __restrict__ adj, uint32_t* __restrict__ bm){
  int idx = blockIdx.x * 256 + threadIdx.x;
  if (idx >= GN * WPR) return;
  int row = idx / WPR, w = idx - row * WPR;
  int j0 = w * 32;
  uint32_t bits = 0u;
  if (j0 < GN) {
    const int* a = adj + (size_t)row * GN + j0;
    int lim = GN - j0;
    if (lim >= 32) {
      const int4* a4 = (const int4*)a;
      #pragma unroll
      for (int g = 0; g < 8; ++g) {
        int4 v = a4[g];
        bits |= (v.x != 0 ? 1u : 0u) << (4*g);
        bits |= (v.y != 0 ? 1u : 0u) << (4*g + 1);
        bits |= (v.z != 0 ? 1u : 0u) << (4*g + 2);
        bits |= (v.w != 0 ? 1u : 0u) << (4*g + 3);
      }
    } else {
      for (int b = 0; b < lim; ++b) bits |= (a[b] != 0 ? 1u : 0u) << b;
    }
  }
  bm[idx] = bits;
}

// ---- x (f32) -> A-tiled bf16 ----
__global__ void k_xtile(const float* __restrict__ x, uint32_t* __restrict__ xt){
  int idx = blockIdx.x * 256 + threadIdx.x;      // 375*16*256 exact
  int e = idx & 3, lane = (idx >> 2) & 63, kt = (idx >> 8) & 15, rt = idx >> 12;
  int g = lane >> 4, r = lane & 15;
  int k0 = kt*32 + kmap(g, e);
  const float* xp = x + (size_t)(rt*16 + r) * GFIN + k0;
  xt[idx] = packbf(xp[0], xp[1]);
}

// ---- W1 -> B-tiled bf16 ----
__global__ void k_wtile1(const float* __restrict__ W1, uint32_t* __restrict__ Wb1){
  int idx = blockIdx.x * 256 + threadIdx.x;      // 131072 exact
  int e = idx & 3, lane = (idx >> 2) & 63, n = (idx >> 8) & 3, kt = (idx >> 10) & 15, h = idx >> 14;
  int g = lane >> 4, col = n*16 + (lane & 15);
  int k0 = kt*32 + kmap(g, e);
  const float* wp = W1 + ((size_t)h*GFIN + k0) * 64 + col;
  Wb1[idx] = packbf(wp[0], wp[64]);
}

// ---- W2 -> B-tiled bf16, cols padded to 64 ----
__global__ void k_wtile2(const float* __restrict__ W2, uint32_t* __restrict__ Wb2){
  int idx = blockIdx.x * 256 + threadIdx.x;      // 16384 exact
  int e = idx & 3, lane = (idx >> 2) & 63, n = (idx >> 8) & 3, kt = idx >> 10;
  int g = lane >> 4, col = n*16 + (lane & 15);
  int k0 = kt*32 + kmap(g, e);
  float v0 = (col < GNC) ? W2[(size_t)k0*GNC + col]     : 0.f;
  float v1 = (col < GNC) ? W2[(size_t)(k0+1)*GNC + col] : 0.f;
  Wb2[idx] = packbf(v0, v1);
}

// ---- MFMA GEMM -> Wh tiled bf16 (optional literal ones-column) + scores ----
__global__ __launch_bounds__(256) void k_gemm_mfma(
    const uint32_t* __restrict__ At, const uint32_t* __restrict__ Bt,
    const float* __restrict__ asv, const float* __restrict__ atv,
    uint32_t* __restrict__ Wt, float* __restrict__ ss, float* __restrict__ st,
    int ones_col){
  int lane = threadIdx.x & 63;
  int wid  = threadIdx.x >> 6;
  int h  = blockIdx.y;
  int rt = blockIdx.x * 4 + wid;
  if (rt >= NRT) return;
  int g = lane >> 4, r = lane & 15;
  const uint32_t* Ab = At + (size_t)rt * 16 * 256 + lane * 4;
  const uint32_t* Bb = Bt + (size_t)h * 16 * 1024 + lane * 4;
  float4v acc[4];
  #pragma unroll
  for (int n = 0; n < 4; ++n) acc[n] = (float4v){0,0,0,0};
  for (int kt = 0; kt < 16; ++kt) {
    union { uint32_t u4[4]; short8v s; } A;
    *(uint4*)A.u4 = *(const uint4*)(Ab + kt*256);
    #pragma unroll
    for (int n = 0; n < 4; ++n) {
      union { uint32_t u4[4]; short8v s; } B;
      *(uint4*)B.u4 = *(const uint4*)(Bb + kt*1024 + n*256);
      acc[n] = __builtin_amdgcn_mfma_f32_16x16x32_bf16(A.s, B.s, acc[n], 0, 0, 0);
    }
  }
  int row0 = rt * 16;
  int t01  = (row0 & 16) ? 2 : 0;
  uint32_t* dst = Wt + ((size_t)h*NT + (row0 >> 5)) * 1024 + lane*4 + t01;
  #pragma unroll
  for (int n = 0; n < 4; ++n) {
    uint2 val;
    if (n*16 + r == ones_col) val = make_uint2(0x3F803F80u, 0x3F803F80u);
    else val = make_uint2(packbf(acc[n][0], acc[n][1]), packbf(acc[n][2], acc[n][3]));
    *(uint2*)(dst + n*256) = val;
  }
  float av[4], tv[4];
  #pragma unroll
  for (int n = 0; n < 4; ++n) { av[n] = asv[h*64 + n*16 + r]; tv[n] = atv[h*64 + n*16 + r]; }
  float pr[4], pt[4];
  #pragma unroll
  for (int reg = 0; reg < 4; ++reg) {
    float a = 0.f, b = 0.f;
    #pragma unroll
    for (int n = 0; n < 4; ++n) { a = fmaf(av[n], acc[n][reg], a); b = fmaf(tv[n], acc[n][reg], b); }
    #pragma unroll
    for (int d = 1; d < 16; d <<= 1) { a += __shfl_xor(a, d, 64); b += __shfl_xor(b, d, 64); }
    pr[reg] = a; pt[reg] = b;
  }
  if (r < 4) {
    ss[(size_t)h*GN + row0 + 4*g + r] = pr[r];
    st[(size_t)h*GN + row0 + 4*g + r] = pt[r];
  }
}

// ---- column stats: p=exp(s), q=exp(0.2 s) (stride PQS) ----
__global__ void k_stats(const float* __restrict__ s_tgt, float* __restrict__ p,
                        float* __restrict__ q){
  int h = blockIdx.x;
  for (int n = threadIdx.x; n < GN; n += 256) {
    float s = s_tgt[(size_t)h*GN + n];
    p[(size_t)h*PQS + n] = expf(s);
    q[(size_t)h*PQS + n] = expf(0.2f * s);
  }
}

// scale-free weight: wv = bit ? max(pj, ti*qj) : 0   (row factor exp(si) cancels)
__device__ __forceinline__ void build_A2(uint32_t bw, int g, float ti,
    const float4& pl, const float4& pH, const float4& ql, const float4& qH,
    uint32_t A[4]){
  uint32_t nl = (bw >> (4*g)) & 0xFu;
  uint32_t nh = (bw >> (16 + 4*g)) & 0xFu;
  float wv[8];
  wv[0] = (nl & 1u) ? fmaxf(pl.x, ti*ql.x) : 0.f;
  wv[1] = (nl & 2u) ? fmaxf(pl.y, ti*ql.y) : 0.f;
  wv[2] = (nl & 4u) ? fmaxf(pl.z, ti*ql.z) : 0.f;
  wv[3] = (nl & 8u) ? fmaxf(pl.w, ti*ql.w) : 0.f;
  wv[4] = (nh & 1u) ? fmaxf(pH.x, ti*qH.x) : 0.f;
  wv[5] = (nh & 2u) ? fmaxf(pH.y, ti*qH.y) : 0.f;
  wv[6] = (nh & 4u) ? fmaxf(pH.z, ti*qH.z) : 0.f;
  wv[7] = (nh & 8u) ? fmaxf(pH.w, ti*qH.w) : 0.f;
  #pragma unroll
  for (int t = 0; t < 4; ++t) A[t] = cvtpk(wv[2*t], wv[2*t+1]);
}

// ---- attention: combo-major grid (XCD-pinned), 32 rows/wave, bf16 partials.
//      ONES: Z via register ones-tile MFMA (attn1). !ONES: Z is B col47 (attn2). ----
template<int CW, int NH, int KC, int NTILES, bool ONES>
__global__ __launch_bounds__(256, 4) void k_attn_t(
    const uint32_t* __restrict__ bm, const uint32_t* __restrict__ Wt,
    const float* __restrict__ ss, const float* __restrict__ p,
    const float* __restrict__ q,
    uint32_t* __restrict__ part, float* __restrict__ Zp){
  int lane = threadIdx.x & 63;
  int wid  = threadIdx.x >> 6;
  constexpr int NB = NH * KC;        // NB % 8 == 0 -> (h,ch) pinned to one XCD
  int combo = blockIdx.x % NB;
  int x     = blockIdx.x / NB;
  int h  = combo / KC;
  int ch = combo % KC;
  int row0 = x * 128 + wid * 32;
  int g = lane >> 4, r = lane & 15;
  int ra = row0 + r, rb = ra + 16;
  int rac = ra < GN-1 ? ra : GN-1;
  int rbc = rb < GN-1 ? rb : GN-1;
  float tia = expf(-0.8f * ss[(size_t)h*GN + rac]);
  float tib = expf(-0.8f * ss[(size_t)h*GN + rbc]);
  const float* ph = p + (size_t)h * PQS;
  const float* qh = q + (size_t)h * PQS;
  const uint32_t* bma = bm + (size_t)rac * WPR;
  const uint32_t* bmb = bm + (size_t)rbc * WPR;
  const uint32_t* wt = Wt + (size_t)h * NT * 1024;
  float4v accA[NTILES], accB[NTILES];
  #pragma unroll
  for (int n = 0; n < NTILES; ++n) { accA[n] = (float4v){0,0,0,0}; accB[n] = (float4v){0,0,0,0}; }
  float4v azA = (float4v){0,0,0,0}, azB = (float4v){0,0,0,0};
  union { uint32_t u4[4]; short8v s; } Bones;
  if (ONES) {
    uint32_t ov = (r == 0) ? 0x3F803F80u : 0u;
    Bones.u4[0] = ov; Bones.u4[1] = ov; Bones.u4[2] = ov; Bones.u4[3] = ov;
  }
  const int w0 = ch * CW;
  for (int wb = 0; wb < CW/4; ++wb) {
    uint4 b4a = *(const uint4*)(bma + w0 + wb*4);
    uint4 b4b = *(const uint4*)(bmb + w0 + wb*4);
    uint32_t ba[4] = {b4a.x, b4a.y, b4a.z, b4a.w};
    uint32_t bb[4] = {b4b.x, b4b.y, b4b.z, b4b.w};
    #pragma unroll
    for (int e = 0; e < 4; ++e) {
      int w = w0 + wb*4 + e;
      int jb = w * 32;
      float4 pl = *(const float4*)(ph + jb + 4*g);
      float4 pH = *(const float4*)(ph + jb + 16 + 4*g);
      float4 ql = *(const float4*)(qh + jb + 4*g);
      float4 qH = *(const float4*)(qh + jb + 16 + 4*g);
      union { uint32_t u4[4]; short8v s; } Aa, Ab;
      build_A2(ba[e], g, tia, pl, pH, ql, qH, Aa.u4);
      build_A2(bb[e], g, tib, pl, pH, ql, qH, Ab.u4);
      const uint32_t* tb = wt + (size_t)w * 1024 + lane * 4;
      #pragma unroll
      for (int n = 0; n < NTILES; ++n) {
        union { uint32_t u4[4]; short8v s; } B;
        *(uint4*)B.u4 = *(const uint4*)(tb + n*256);
        accA[n] = __builtin_amdgcn_mfma_f32_16x16x32_bf16(Aa.s, B.s, accA[n], 0, 0, 0);
        accB[n] = __builtin_amdgcn_mfma_f32_16x16x32_bf16(Ab.s, B.s, accB[n], 0, 0, 0);
      }
      if (ONES) {
        azA = __builtin_amdgcn_mfma_f32_16x16x32_bf16(Aa.s, Bones.s, azA, 0, 0, 0);
        azB = __builtin_amdgcn_mfma_f32_16x16x32_bf16(Ab.s, Bones.s, azB, 0, 0, 0);
      }
    }
  }
  // bf16-packed partial store: row-pairs per dword
  constexpr int PST = NTILES * 16;
  size_t pb = ((size_t)(ch * NH + h)) * GNP2;
  int pra = (row0 >> 1) + 2*g;
  #pragma unroll
  for (int n = 0; n < NTILES; ++n) {
    part[(pb + pra    )*PST + n*16 + r] = packbf(accA[n][0], accA[n][1]);
    part[(pb + pra + 1)*PST + n*16 + r] = packbf(accA[n][2], accA[n][3]);
  }
  if (row0 + 16 < GN) {
    int prb = pra + 8;
    #pragma unroll
    for (int n = 0; n < NTILES; ++n) {
      part[(pb + prb    )*PST + n*16 + r] = packbf(accB[n][0], accB[n][1]);
      part[(pb + prb + 1)*PST + n*16 + r] = packbf(accB[n][2], accB[n][3]);
    }
  }
  if (ONES && r == 0) {
    size_t zb = ((size_t)(ch * NH + h)) * GN;
    #pragma unroll
    for (int reg = 0; reg < 4; ++reg) {
      Zp[zb + row0 + 4*g + reg] = azA[reg];
      if (row0 + 16 < GN) Zp[zb + row0 + 16 + 4*g + reg] = azB[reg];
    }
  }
}

// ---- combine L1 chunks (bf16 pairs): normalize, ELU, h1 A-tile write ----
__global__ void k_reduce1(const uint32_t* __restrict__ part1, const float* __restrict__ Zp1,
                          uint32_t* __restrict__ h1t){
  int idx = blockIdx.x * 256 + threadIdx.x;
  if (idx >= GNH*GNP2*64) return;
  int o = idx & 63;
  int t = idx >> 6;
  int pr = t % GNP2;
  int h = t / GNP2;
  float s0 = 0.f, s1 = 0.f, z0 = 0.f, z1 = 0.f;
  #pragma unroll
  for (int c = 0; c < KC1; ++c) {
    uint32_t dw = part1[(((size_t)(c*GNH + h))*GNP2 + pr)*64 + o];
    s0 += bf2f((uint16_t)dw);
    s1 += bf2f((uint16_t)(dw >> 16));
    size_t zb = ((size_t)(c*GNH + h))*GN + 2*pr;
    z0 += Zp1[zb]; z1 += Zp1[zb + 1];
  }
  float v0 = s0 / z0, v1 = s1 / z1;
  v0 = v0 > 0.f ? v0 : (expf(v0) - 1.f);
  v1 = v1 > 0.f ? v1 : (expf(v1) - 1.f);
  int n0 = 2*pr;
  int rt = n0 >> 4, rr = n0 & 15;
  int k = h*64 + o;
  int kt = k >> 5, joff = k & 31;
  int g, tt, b;
  if (joff < 16) { g = joff >> 2; tt = (joff & 3) >> 1;        b = joff & 1; }
  else { int jo = joff - 16; g = jo >> 2; tt = 2 + ((jo & 3) >> 1); b = jo & 1; }
  size_t dw0 = ((size_t)(rt*16 + kt))*256 + (g*16 + rr)*4 + tt;
  ((uint16_t*)h1t)[dw0*2 + b]     = f2bf(v0);
  ((uint16_t*)h1t)[(dw0+4)*2 + b] = f2bf(v1);
}

// ---- combine L2 chunks: normalize (Z = col 47), f32 logits ----
__global__ void k_reduce2(const uint32_t* __restrict__ part2, float* __restrict__ out){
  int idx = blockIdx.x * 256 + threadIdx.x;
  if (idx >= GN * GNC) return;
  int n = idx / GNC, c = idx - n * GNC;
  int pr = n >> 1, half = n & 1;
  float s = 0.f, z = 0.f;
  #pragma unroll 8
  for (int ch = 0; ch < KC2; ++ch) {
    const uint32_t* row = part2 + ((size_t)ch * GNP2 + pr) * 48;
    uint32_t dS = row[c], dZ = row[47];
    s += half ? bf2f((uint16_t)(dS >> 16)) : bf2f((uint16_t)dS);
    z += half ? bf2f((uint16_t)(dZ >> 16)) : bf2f((uint16_t)dZ);
  }
  out[idx] = s / z;
}

// ---- adjacency echo (f32), written LAST over all scratch ----
__global__ void k_echo(const uint32_t* __restrict__ bm, float* __restrict__ echo){
  int idx = blockIdx.x * 256 + threadIdx.x;
  if (idx >= GN * WPR) return;
  int row = idx / WPR, w = idx - row * WPR;
  int j0 = w * 32;
  if (j0 >= GN) return;
  uint32_t bits = bm[idx];
  float* dst = echo + (size_t)row * GN + j0;
  int lim = GN - j0;
  if (lim >= 32) {
    float4* d4 = (float4*)dst;
    #pragma unroll
    for (int g = 0; g < 8; ++g) {
      float4 f;
      f.x = ((bits >> (4*g+0)) & 1u) ? 1.f : 0.f;
      f.y = ((bits >> (4*g+1)) & 1u) ? 1.f : 0.f;
      f.z = ((bits >> (4*g+2)) & 1u) ? 1.f : 0.f;
      f.w = ((bits >> (4*g+3)) & 1u) ? 1.f : 0.f;
      d4[g] = f;
    }
  } else {
    for (int b = 0; b < lim; ++b) dst[b] = ((bits >> b) & 1u) ? 1.f : 0.f;
  }
}

extern "C" void kernel_launch(void* const* d_in, const int* in_sizes, int n_in,
                              void* d_out, int out_size, void* d_ws, size_t ws_size,
                              hipStream_t stream){
  const float* x   = (const float*)d_in[0];
  const int*   adj = (const int*)d_in[1];
  const float* W1  = (const float*)d_in[2];
  const float* as1 = (const float*)d_in[3];
  const float* at1 = (const float*)d_in[4];
  const float* W2  = (const float*)d_in[5];
  const float* as2 = (const float*)d_in[6];
  const float* at2 = (const float*)d_in[7];
  float* out  = (float*)d_out;                    // f32 logits [6000,40]
  float* echo = out + (size_t)GN * GNC;           // f32 adj echo [6000,6000]
  (void)in_sizes; (void)n_in; (void)out_size; (void)ws_size;

  // scratch in echo region (dead before k_echo overwrites)
  uint32_t* part1u = (uint32_t*)echo;                              // 12.288M dw
  float*    Zp1    = (float*)(part1u + (size_t)KC1*GNH*GNP2*64);   // 384K f32
  uint32_t* part2u = (uint32_t*)(Zp1 + (size_t)KC1*GNH*GN);        // 3.456M dw
  uint32_t* h1t    = part2u + (size_t)KC2*GNP2*48;                 // 1.536M dw
  uint32_t* xt     = h1t + (size_t)NRT*16*256;                     // 1.536M dw
  // total ~77 MB <= 144 MB

  char* wsb = (char*)d_ws;
  size_t off = 0;
  auto alloc = [&](size_t bytes) -> void* {
    void* r = wsb + off;
    off = (off + bytes + 255) & ~(size_t)255;
    return r;
  };
  uint32_t* bm   = (uint32_t*)alloc((size_t)GN * WPR * 4);
  uint32_t* Wt1  = (uint32_t*)alloc((size_t)GNH * NT * 1024 * 4);
  uint32_t* Wt2  = (uint32_t*)alloc((size_t)NT * 1024 * 4);
  uint32_t* Wb1  = (uint32_t*)alloc((size_t)GNH * 16 * 1024 * 4);
  uint32_t* Wb2  = (uint32_t*)alloc((size_t)16 * 1024 * 4);
  float*    as2f = (float*)alloc(64 * 4);
  float*    at2f = (float*)alloc(64 * 4);
  float*    ss1  = (float*)alloc((size_t)GNH * GN * 4);
  float*    st1  = (float*)alloc((size_t)GNH * GN * 4);
  float*    p1   = (float*)alloc((size_t)GNH * PQS * 4);
  float*    q1   = (float*)alloc((size_t)GNH * PQS * 4);
  float*    ss2  = (float*)alloc((size_t)GN * 4);
  float*    st2  = (float*)alloc((size_t)GN * 4);
  float*    p2   = (float*)alloc((size_t)PQS * 4);
  float*    q2   = (float*)alloc((size_t)PQS * 4);

  const int NX = (GN + 127) / 128;    // 47 row-blocks (attn)

  hipLaunchKernelGGL(k_prep, dim3(192), dim3(256), 0, stream,
      as2, at2, as2f, at2f, Wt1, Wt2, p1, q1, p2, q2);
  hipLaunchKernelGGL(k_bitmask, dim3(GN*WPR/256), dim3(256), 0, stream, adj, bm);
  hipLaunchKernelGGL(k_xtile, dim3(NRT*16*256/256), dim3(256), 0, stream, x, xt);
  hipLaunchKernelGGL(k_wtile1, dim3(512), dim3(256), 0, stream, W1, Wb1);
  hipLaunchKernelGGL(k_wtile2, dim3(64), dim3(256), 0, stream, W2, Wb2);
  hipLaunchKernelGGL(k_gemm_mfma, dim3((NRT+3)/4, GNH), dim3(256), 0, stream,
      xt, Wb1, as1, at1, Wt1, ss1, st1, -1);
  hipLaunchKernelGGL(k_stats, dim3(GNH), dim3(256), 0, stream, st1, p1, q1);
  hipLaunchKernelGGL((k_attn_t<CW1, GNH, KC1, 4, true>), dim3(NX * GNH * KC1), dim3(256), 0, stream,
      bm, Wt1, ss1, p1, q1, part1u, Zp1);
  hipLaunchKernelGGL(k_reduce1, dim3(GNH*GNP2*64/256), dim3(256), 0, stream,
      part1u, Zp1, h1t);
  hipLaunchKernelGGL(k_gemm_mfma, dim3((NRT+3)/4, 1), dim3(256), 0, stream,
      h1t, Wb2, as2f, at2f, Wt2, ss2, st2, 47);
  hipLaunchKernelGGL(k_stats, dim3(1), dim3(256), 0, stream, st2, p2, q2);
  hipLaunchKernelGGL((k_attn_t<CW2, 1, KC2, 3, false>), dim3(NX * KC2), dim3(256), 0, stream,
      bm, Wt2, ss2, p2, q2, part2u, (float*)nullptr);
  hipLaunchKernelGGL(k_reduce2, dim3((GN*GNC+255)/256), dim3(256), 0, stream,
      part2u, out);
  hipLaunchKernelGGL(k_echo, dim3(GN*WPR/256), dim3(256), 0, stream, bm, echo);
}